// Round 4
// baseline (5742.768 us; speedup 1.0000x reference)
//
#include <hip/hip_runtime.h>
#include <hip/hip_bf16.h>

#define GG 2048
#define PP 10
#define HHC 128
#define NSTEP 25
#define NROW (GG*PP)      // 20480
#define XST 64            // x row: 64 floats = 256B, line-aligned
#define KTOT 208          // 64 (x) + 2 (ai) + 2 pad + 128 (hx) + 12 pad
#define FTP 40            // featT col stride (40 rows/block)
#define WBP 36            // wbuf row pad

__device__ __forceinline__ float4 f4fma(float s, const float4 w, float4 a){
  a.x = fmaf(s, w.x, a.x); a.y = fmaf(s, w.y, a.y);
  a.z = fmaf(s, w.z, a.z); a.w = fmaf(s, w.w, a.w);
  return a;
}
__device__ __forceinline__ float4 f4add(float4 a, float4 b){
  a.x+=b.x; a.y+=b.y; a.z+=b.z; a.w+=b.w; return a;
}
__device__ __forceinline__ float4 sx4(float4 v, int m){
  float4 r; r.x=__shfl_xor(v.x,m); r.y=__shfl_xor(v.y,m);
  r.z=__shfl_xor(v.z,m); r.w=__shfl_xor(v.w,m); return r;
}
__device__ __forceinline__ float sigf(float x){ return 1.f/(1.f+__expf(-x)); }
__device__ __forceinline__ float tanhf_(float x){ return 2.f/(1.f+__expf(-2.f*x)) - 1.f; }
__device__ __forceinline__ float4 sig4(float4 v){
  v.x=sigf(v.x); v.y=sigf(v.y); v.z=sigf(v.z); v.w=sigf(v.w); return v;
}
__device__ __forceinline__ float4 tanh4(float4 v){
  v.x=tanhf_(v.x); v.y=tanhf_(v.y); v.z=tanhf_(v.z); v.w=tanhf_(v.w); return v;
}

// 8-row FMA: acc[0..3] <- a0 rows, acc[4..7] <- a1 rows
#define ROWFMA8(ACC, A0, A1, WV) \
  ACC[0]=f4fma(A0.x,WV,ACC[0]); ACC[1]=f4fma(A0.y,WV,ACC[1]); \
  ACC[2]=f4fma(A0.z,WV,ACC[2]); ACC[3]=f4fma(A0.w,WV,ACC[3]); \
  ACC[4]=f4fma(A1.x,WV,ACC[4]); ACC[5]=f4fma(A1.y,WV,ACC[5]); \
  ACC[6]=f4fma(A1.z,WV,ACC[6]); ACC[7]=f4fma(A1.w,WV,ACC[7]);

// ---------------------------------------------------------------------------
// Weight prep: wT[s][k][j], k-major; k<66 = wih, 68..195 = whh, else 0
// ---------------------------------------------------------------------------
__global__ __launch_bounds__(256) void prep_weights(
    const float* __restrict__ wih, const float* __restrict__ whh,
    const float* __restrict__ bih, const float* __restrict__ bhh,
    float* __restrict__ wT, float* __restrict__ bsum)
{
  long id = (long)blockIdx.x*256 + threadIdx.x;   // 25*208*512 total
  int j = (int)(id & 511);
  long r = id >> 9;
  int k = (int)(r % KTOT);
  int s = (int)(r / KTOT);
  float v = 0.f;
  if (k < 66) v = wih[((long)s*512 + j)*66 + k];
  else if (k >= 68 && k < 196) v = whh[((long)s*512 + j)*128 + (k-68)];
  wT[id] = v;
  if (k == 0) bsum[(long)s*512 + j] = bih[(long)s*512 + j] + bhh[(long)s*512 + j];
}

// reduce over ks (xor 1,2,4), add bias, L2-normalize over dq (xor 8,16,32)
__device__ __forceinline__ void reduce_norm8(float4 acc[8], const float* bsel, int dq)
{
  #pragma unroll
  for (int j=0;j<8;j++){
    acc[j] = f4add(acc[j], sx4(acc[j],1));
    acc[j] = f4add(acc[j], sx4(acc[j],2));
    acc[j] = f4add(acc[j], sx4(acc[j],4));
  }
  float4 bb = ((const float4*)bsel)[dq];
  #pragma unroll
  for (int j=0;j<8;j++){
    acc[j].x+=bb.x; acc[j].y+=bb.y; acc[j].z+=bb.z; acc[j].w+=bb.w;
    float ss = acc[j].x*acc[j].x + acc[j].y*acc[j].y
             + acc[j].z*acc[j].z + acc[j].w*acc[j].w;
    ss += __shfl_xor(ss,8); ss += __shfl_xor(ss,16); ss += __shfl_xor(ss,32);
    float sc = 1.f/fmaxf(sqrtf(ss),1e-12f);
    acc[j].x*=sc; acc[j].y*=sc; acc[j].z*=sc; acc[j].w*=sc;
  }
}

// ---------------------------------------------------------------------------
// Graph conv: 4 graphs/block, 640 threads = 2 path-groups x 320.
// matmul decomp (per group): u = t%320: rb = u>>6 (8 rows), dq=(u>>3)&7, ks=u&7
//   grp 0 -> pos path, grp 1 -> neg path. acc[8] = 8 rows x 4 cols.
// agg decomp: t = agl*160 + ap*16 + adq*2 + ah
// featT[k][row40]: deep rows 0..191 = 6 agg blocks, 192..223 self-pos,
//                  224..255 self-neg; base rows 0..31 aggP, 32..63 aggN, 64..95 h0
// ---------------------------------------------------------------------------
__global__ __launch_bounds__(640,5) void graphconv(
    const float* __restrict__ h0, const float* __restrict__ add_info,
    const float* __restrict__ wpb, const float* __restrict__ bpb,
    const float* __restrict__ wnb, const float* __restrict__ bnb,
    const float* __restrict__ wpd, const float* __restrict__ bpd,
    const float* __restrict__ wnd, const float* __restrict__ bnd,
    const int* __restrict__ pos_adj, const int* __restrict__ neg_adj,
    float* __restrict__ xout)
{
  __shared__ __align__(16) float featT[256][FTP];
  __shared__ __align__(16) float wbuf[2][64][WBP];
  __shared__ __align__(16) float h0s[4][PP][32];
  __shared__ __align__(16) float hps[4][PP][32];
  __shared__ __align__(16) float hns[4][PP][32];
  __shared__ float Afp[4][PP][10];
  __shared__ float Afn[4][PP][10];
  __shared__ float degpr[4][PP], degnr[4][PP], degpc[4][PP], degnc[4][PP];

  const int t = threadIdx.x;
  const int grp = t/320;          // wave-uniform (5 waves per group)
  const int u = t - grp*320;
  const int rb = u>>6;            // 0..4, wave-uniform
  const int dq = (u>>3)&7;
  const int ks = u&7;
  const int agl = t/160;
  const int arem = t%160;
  const int ap = arem>>4;
  const int adq = (arem>>1)&7;
  const int ah = arem&1;
  const long g0 = (long)blockIdx.x*4;

  // ---- init: adjacency, h0 (row-major + transposed) ----
  if (t<400){
    int gg_ = t/100, e = t%100, rr=e/10, cc=e%10;
    float z = (rr==cc)?0.f:1.f;
    Afp[gg_][rr][cc] = z*(float)pos_adj[(g0+gg_)*100 + e];
    Afn[gg_][rr][cc] = z*(float)neg_adj[(g0+gg_)*100 + e];
  }
  if (t<320){
    int gg_ = t/80, pp_ = (t%80)>>3, dd = t&7;
    float4 hv = ((const float4*)(h0 + (g0+gg_)*PP*32))[pp_*8+dd];
    *(float4*)&h0s[gg_][pp_][dd*4] = hv;
    int col = gg_*10+pp_;
    featT[64+dd*4+0][col]=hv.x; featT[64+dd*4+1][col]=hv.y;
    featT[64+dd*4+2][col]=hv.z; featT[64+dd*4+3][col]=hv.w;
  }
  __syncthreads();
  if (t<40){
    int gg_=t/10, pp_=t%10;
    float s0=0,s1=0,s2=0,s3=0;
    for(int q=0;q<10;q++){
      s0+=Afp[gg_][pp_][q]; s1+=Afn[gg_][pp_][q];
      s2+=Afp[gg_][q][pp_]; s3+=Afn[gg_][q][pp_];
    }
    degpr[gg_][pp_]=1.f/fmaxf(s0,1.f);
    degnr[gg_][pp_]=1.f/fmaxf(s1,1.f);
    degpc[gg_][pp_]=1.f/fmaxf(s2,1.f);
    degnc[gg_][pp_]=1.f/fmaxf(s3,1.f);
  }
  __syncthreads();

  // ---- base aggregation (transposed write) + base weight staging ----
  {
    float4 bP=make_float4(0,0,0,0), bN=bP;
    #pragma unroll
    for (int qi=0; qi<5; ++qi){
      int q = ah*5+qi;
      float4 hv = *(const float4*)&h0s[agl][q][adq*4];
      bP = f4fma(Afp[agl][ap][q], hv, bP);
      bN = f4fma(Afn[agl][ap][q], hv, bN);
    }
    bP = f4add(bP, sx4(bP,1));
    bN = f4add(bN, sx4(bN,1));
    int col = agl*10+ap;
    if (ah==0){
      float s = degpr[agl][ap];
      featT[adq*4+0][col]=bP.x*s; featT[adq*4+1][col]=bP.y*s;
      featT[adq*4+2][col]=bP.z*s; featT[adq*4+3][col]=bP.w*s;
    } else {
      float s = degnr[agl][ap];
      featT[32+adq*4+0][col]=bN.x*s; featT[32+adq*4+1][col]=bN.y*s;
      featT[32+adq*4+2][col]=bN.z*s; featT[32+adq*4+3][col]=bN.w*s;
    }
  }
  for (int idx=t; idx<1024; idx+=640){
    int path=idx>>9, rem2=idx&511, kk=rem2>>3, dqq=rem2&7;
    const float* ws_ = path? wnb : wpb;
    *(float4*)&wbuf[path][kk][dqq*4] = ((const float4*)(ws_ + kk*32))[dqq];
  }
  __syncthreads();

  // ---- base matmul: K=64, own path ----
  float4 acc[8];
  #pragma unroll
  for (int j=0;j<8;j++) acc[j]=make_float4(0,0,0,0);
  #pragma unroll
  for (int i=0;i<8;i++){
    int kk = i*8+ks;
    int row = grp? (kk+32) : (kk + ((i>=4)?32:0));
    float4 w  = *(const float4*)&wbuf[grp][kk][dq*4];
    float4 a0 = *(const float4*)&featT[row][rb*8];
    float4 a1 = *(const float4*)&featT[row][rb*8+4];
    ROWFMA8(acc, a0, a1, w);
  }
  reduce_norm8(acc, grp? bnb : bpb, dq);
  __syncthreads();     // all featT/wbuf reads done
  #pragma unroll
  for (int j=0;j<8;j++){
    if (ks==j){
      int r = rb*8+j;
      int gg_ = r/10, pp_ = r%10;
      float* hdst = grp? &hns[gg_][pp_][dq*4] : &hps[gg_][pp_][dq*4];
      *(float4*)hdst = acc[j];
      int rowbase = grp? 224 : 192;
      featT[rowbase+dq*4+0][r]=acc[j].x;
      featT[rowbase+dq*4+1][r]=acc[j].y;
      featT[rowbase+dq*4+2][r]=acc[j].z;
      featT[rowbase+dq*4+3][r]=acc[j].w;
    }
  }
  __syncthreads();

  // ---- deep layers ----
  #pragma unroll 1
  for (int layer=0; layer<2; ++layer){
    // aggregation (6 blocks, transposed write into featT rows 0..191)
    {
      float4 b0=make_float4(0,0,0,0),b1=b0,b2=b0,b3=b0,b4=b0,b5=b0;
      #pragma unroll
      for (int qi=0; qi<5; ++qi){
        int q = ah*5+qi;
        float4 hp = *(const float4*)&hps[agl][q][adq*4];
        float4 hn = *(const float4*)&hns[agl][q][adq*4];
        float apq=Afp[agl][ap][q], anq=Afn[agl][ap][q];
        float apT=Afp[agl][q][ap], anT=Afn[agl][q][ap];
        b0=f4fma(apq,hp,b0); b1=f4fma(anq,hn,b1); b2=f4fma(apq,hn,b2);
        b3=f4fma(anq,hp,b3); b4=f4fma(apT,hp,b4); b5=f4fma(anT,hn,b5);
      }
      b0=f4add(b0,sx4(b0,1)); b1=f4add(b1,sx4(b1,1)); b2=f4add(b2,sx4(b2,1));
      b3=f4add(b3,sx4(b3,1)); b4=f4add(b4,sx4(b4,1)); b5=f4add(b5,sx4(b5,1));
      int col = agl*10+ap;
      if (ah==0){
        float s0=degpr[agl][ap], s1=degnr[agl][ap];
        featT[ adq*4+0][col]=b0.x*s0; featT[ adq*4+1][col]=b0.y*s0;
        featT[ adq*4+2][col]=b0.z*s0; featT[ adq*4+3][col]=b0.w*s0;
        featT[32+adq*4+0][col]=b1.x*s1; featT[32+adq*4+1][col]=b1.y*s1;
        featT[32+adq*4+2][col]=b1.z*s1; featT[32+adq*4+3][col]=b1.w*s1;
        featT[64+adq*4+0][col]=b2.x*s0; featT[64+adq*4+1][col]=b2.y*s0;
        featT[64+adq*4+2][col]=b2.z*s0; featT[64+adq*4+3][col]=b2.w*s0;
      } else {
        float s1=degnr[agl][ap], s2=degpc[agl][ap], s3=degnc[agl][ap];
        featT[ 96+adq*4+0][col]=b3.x*s1; featT[ 96+adq*4+1][col]=b3.y*s1;
        featT[ 96+adq*4+2][col]=b3.z*s1; featT[ 96+adq*4+3][col]=b3.w*s1;
        featT[128+adq*4+0][col]=b4.x*s2; featT[128+adq*4+1][col]=b4.y*s2;
        featT[128+adq*4+2][col]=b4.z*s2; featT[128+adq*4+3][col]=b4.w*s2;
        featT[160+adq*4+0][col]=b5.x*s3; featT[160+adq*4+1][col]=b5.y*s3;
        featT[160+adq*4+2][col]=b5.z*s3; featT[160+adq*4+3][col]=b5.w*s3;
      }
    }
    __syncthreads();

    #pragma unroll
    for (int j=0;j<8;j++) acc[j]=make_float4(0,0,0,0);
    const float* wpl = wpd + layer*7168;
    const float* wnl = wnd + layer*7168;
    #pragma unroll
    for (int chunk=0; chunk<4; ++chunk){
      const int c0 = chunk*56;
      for (int idx=t; idx<896; idx+=640){
        int path=idx/448, rem2=idx%448, kk=rem2>>3, dqq=rem2&7;
        const float* ws_ = path? wnl : wpl;
        *(float4*)&wbuf[path][kk][dqq*4] = ((const float4*)(ws_ + (c0+kk)*32))[dqq];
      }
      __syncthreads();
      #pragma unroll
      for (int i=0;i<7;i++){
        int kk = i*8+ks;
        int k = c0 + kk;
        int row = k + ((grp && (c0+i*8 >= 192))? 32 : 0);
        float4 w  = *(const float4*)&wbuf[grp][kk][dq*4];
        float4 a0 = *(const float4*)&featT[row][rb*8];
        float4 a1 = *(const float4*)&featT[row][rb*8+4];
        ROWFMA8(acc, a0, a1, w);
      }
      __syncthreads();
    }

    reduce_norm8(acc, grp? (bnd+layer*32) : (bpd+layer*32), dq);
    if (layer==0){
      #pragma unroll
      for (int j=0;j<8;j++){
        if (ks==j){
          int r = rb*8+j;
          int gg_ = r/10, pp_ = r%10;
          float* hdst = grp? &hns[gg_][pp_][dq*4] : &hps[gg_][pp_][dq*4];
          *(float4*)hdst = acc[j];
          int rowbase = grp? 224 : 192;
          featT[rowbase+dq*4+0][r]=acc[j].x;
          featT[rowbase+dq*4+1][r]=acc[j].y;
          featT[rowbase+dq*4+2][r]=acc[j].z;
          featT[rowbase+dq*4+3][r]=acc[j].w;
        }
      }
      __syncthreads();
    } else {
      // final: write x rows (pos cols 0..31, neg cols 32..63)
      #pragma unroll
      for (int j=0;j<8;j++){
        if (ks==j){
          int r = rb*8+j;
          long gid = g0 + r/10;
          int p_ = r%10;
          long gout = gid/25; int rem = (int)(gid%25);
          long orow = ((long)rem*NROW + gout*PP + p_)*XST;
          ((float4*)(xout + orow))[grp*8 + dq] = acc[j];
        }
      }
    }
  }
}

// ---------------------------------------------------------------------------
// LSTM step: 640 blocks x 256 threads, 32 rows/block.
// thread: cb = t&31 (col quad), gh = (t>>5)&1 (gates {i,f} or {g,o}),
//         rg = t>>6 (0..3) -> rows rg*8..rg*8+7.  acc[2][8] = 2 gates x 8 rows.
// epilogue: shfl_xor(32) swaps gate pairs; gh0 handles rows 0..3, gh1 rows 4..7.
// ---------------------------------------------------------------------------
__global__ __launch_bounds__(256,2) void lstm_step(
    const float* __restrict__ xg, const float* __restrict__ wT,
    const float* __restrict__ bsum, const float* __restrict__ hxin,
    float* __restrict__ hxout, float* __restrict__ cx,
    float* __restrict__ outp, const float* __restrict__ ai,
    const int step, const int last)
{
  __shared__ __align__(16) float xinT[KTOT][36];
  __shared__ __align__(16) float wc[2][8*512];
  const int t = threadIdx.x;
  const int cb = t&31, gh = (t>>5)&1, rg = t>>6;
  const long rbase = (long)blockIdx.x*32;
  const int mdiv = step/5;

  // stage transposed inputs: rows 0..63 x, 64..65 ai, 66..67 z, 68..195 hx, rest z
  for (int idx=t; idx<32*52; idx+=256){
    int r = idx/52, c = idx - r*52;
    float4 v = make_float4(0,0,0,0);
    int k0;
    if (c<16){ v = ((const float4*)xg)[(rbase+r)*16 + c]; k0 = c*4; }
    else if (c==16){
      long rr = rbase + r;
      int g = (int)(rr/10), p = (int)(rr%10);
      const float* aip = ai + (((long)g*5 + mdiv)*10 + p)*2;
      v = make_float4(aip[0], aip[1], 0.f, 0.f);
      k0 = 64;
    }
    else if (c<49){ v = ((const float4*)hxin)[(rbase+r)*32 + (c-17)]; k0 = 68+(c-17)*4; }
    else { k0 = 196+(c-49)*4; }
    xinT[k0+0][r]=v.x; xinT[k0+1][r]=v.y; xinT[k0+2][r]=v.z; xinT[k0+3][r]=v.w;
  }

  float4 acc[2][8];
  {
    float4 b0 = ((const float4*)bsum)[(gh*2  )*32 + cb];
    float4 b1 = ((const float4*)bsum)[(gh*2+1)*32 + cb];
    #pragma unroll
    for (int j=0;j<8;j++){
      acc[0][j] = make_float4(b0.x*0.125f,b0.y*0.125f,b0.z*0.125f,b0.w*0.125f);
      acc[1][j] = make_float4(b1.x*0.125f,b1.y*0.125f,b1.z*0.125f,b1.w*0.125f);
    }
    // note: bias added once per row; 0.125 trick invalid -> fix: add full bias to j only once
  }
  // correct bias init: full bias in each row accumulator
  {
    float4 b0 = ((const float4*)bsum)[(gh*2  )*32 + cb];
    float4 b1 = ((const float4*)bsum)[(gh*2+1)*32 + cb];
    #pragma unroll
    for (int j=0;j<8;j++){ acc[0][j]=b0; acc[1][j]=b1; }
  }

  const float4* wT4 = (const float4*)wT;
  float4* wc4 = (float4*)wc;
  // prologue: stage chunk 0 into buf 0
  #pragma unroll
  for (int n=0;n<4;n++) wc4[t + n*256] = wT4[t + n*256];
  __syncthreads();

  for (int kc=0;kc<26;kc++){
    const int cur = kc&1;
    if (kc<25){
      #pragma unroll
      for (int n=0;n<4;n++){
        int idx = t + n*256;
        wc4[(cur^1)*1024 + idx] = wT4[(long)(kc+1)*1024 + idx];
      }
    }
    const float4* wcb = wc4 + cur*1024;
    #pragma unroll
    for (int kk=0;kk<8;kk++){
      int k = kc*8+kk;
      float4 a0 = *(const float4*)&xinT[k][rg*8];
      float4 a1 = *(const float4*)&xinT[k][rg*8+4];
      float4 w0 = wcb[kk*128 + gh*64      + cb];
      float4 w1 = wcb[kk*128 + gh*64 + 32 + cb];
      ROWFMA8(acc[0], a0, a1, w0);
      ROWFMA8(acc[1], a0, a1, w1);
    }
    __syncthreads();
  }

  // epilogue: gh0 has i,f ; gh1 has g,o (same cb, same rows via lane^32)
  #pragma unroll
  for (int r=0;r<8;r++){
    float4 pA = sx4(acc[0][r],32);
    float4 pB = sx4(acc[1][r],32);
    bool mine = gh ? (r>=4) : (r<4);
    if (mine){
      float4 ig = gh? pA        : acc[0][r];
      float4 fg = gh? pB        : acc[1][r];
      float4 gg = gh? acc[0][r] : pA;
      float4 og = gh? acc[1][r] : pB;
      long R = rbase + rg*8 + r;
      float4 cold = ((const float4*)cx)[R*32+cb];
      float4 iv = sig4(ig), fv = sig4(fg), ov = sig4(og);
      float4 gv = tanh4(gg);
      float4 cn, hn;
      cn.x = fv.x*cold.x + iv.x*gv.x;  cn.y = fv.y*cold.y + iv.y*gv.y;
      cn.z = fv.z*cold.z + iv.z*gv.z;  cn.w = fv.w*cold.w + iv.w*gv.w;
      float4 tc = tanh4(cn);
      hn.x = ov.x*tc.x; hn.y = ov.y*tc.y; hn.z = ov.z*tc.z; hn.w = ov.w*tc.w;
      ((float4*)cx)[R*32+cb] = cn;
      ((float4*)hxout)[R*32+cb] = hn;
      if (last) ((float4*)outp)[R*32+cb] = hn;
    }
  }
}

// ---------------------------------------------------------------------------
extern "C" void kernel_launch(void* const* d_in, const int* in_sizes, int n_in,
                              void* d_out, int out_size, void* d_ws, size_t ws_size,
                              hipStream_t stream)
{
  const float* h0  = (const float*)d_in[0];
  const float* ai  = (const float*)d_in[1];
  const float* wpb = (const float*)d_in[2];
  const float* bpb = (const float*)d_in[3];
  const float* wnb = (const float*)d_in[4];
  const float* bnb = (const float*)d_in[5];
  const float* wpd = (const float*)d_in[6];
  const float* bpd = (const float*)d_in[7];
  const float* wnd = (const float*)d_in[8];
  const float* bnd = (const float*)d_in[9];
  const float* wih = (const float*)d_in[10];
  const float* whh = (const float*)d_in[11];
  const float* bih = (const float*)d_in[12];
  const float* bhh = (const float*)d_in[13];
  const float* hx0 = (const float*)d_in[14];
  const float* cx0 = (const float*)d_in[15];
  const int* padj  = (const int*)d_in[16];
  const int* nadj  = (const int*)d_in[17];
  float* out = (float*)d_out;

  float* ws   = (float*)d_ws;
  float* xbuf = ws;                                     // 25*20480*64
  float* wT   = xbuf + (size_t)NSTEP*NROW*XST;          // 25*208*512
  float* bs   = wT + (size_t)NSTEP*KTOT*512;            // 25*512
  float* hxA  = bs + (size_t)NSTEP*512;                 // 20480*128
  float* hxB  = hxA + (size_t)NROW*HHC;
  float* cxb  = hxB + (size_t)NROW*HHC;

  hipMemcpyAsync(hxA, hx0, sizeof(float)*(size_t)NROW*HHC, hipMemcpyDeviceToDevice, stream);
  hipMemcpyAsync(cxb, cx0, sizeof(float)*(size_t)NROW*HHC, hipMemcpyDeviceToDevice, stream);

  prep_weights<<<10400,256,0,stream>>>(wih,whh,bih,bhh,wT,bs);
  graphconv<<<12800,640,0,stream>>>(h0,ai,wpb,bpb,wnb,bnb,wpd,bpd,wnd,bnd,padj,nadj,xbuf);

  for (int s=0;s<NSTEP;s++){
    const float* hin = (s&1)? hxB : hxA;
    float* hout      = (s&1)? hxA : hxB;
    lstm_step<<<640,256,0,stream>>>(xbuf + (size_t)s*NROW*XST,
                                    wT + (size_t)s*KTOT*512,
                                    bs + (size_t)s*512,
                                    hin, hout, cxb, out, ai, s, (s==NSTEP-1)?1:0);
  }
}

// Round 5
// 2374.932 us; speedup vs baseline: 2.4181x; 2.4181x over previous
//
#include <hip/hip_runtime.h>
#include <hip/hip_bf16.h>

#define GG 2048
#define PP 10
#define HHC 128
#define NSTEP 25
#define NROW (GG*PP)      // 20480
#define XST 64            // x row: 64 floats = 256B, line-aligned
#define FTP 40            // featT col stride
#define WBP 36            // wbuf row pad
#define ASTR 216          // Ahi LDS row stride (bf16 elems): 432B, 16B-aligned, 4-way banks
#define LSTR 136          // Alo LDS row stride: 272B, 16B-aligned, 4-way banks

typedef __attribute__((ext_vector_type(8))) short bf16x8;
typedef __attribute__((ext_vector_type(16))) float f32x16;
typedef unsigned short ushort_t;

__device__ __forceinline__ float4 f4fma(float s, const float4 w, float4 a){
  a.x = fmaf(s, w.x, a.x); a.y = fmaf(s, w.y, a.y);
  a.z = fmaf(s, w.z, a.z); a.w = fmaf(s, w.w, a.w);
  return a;
}
__device__ __forceinline__ float4 f4add(float4 a, float4 b){
  a.x+=b.x; a.y+=b.y; a.z+=b.z; a.w+=b.w; return a;
}
__device__ __forceinline__ float4 sx4(float4 v, int m){
  float4 r; r.x=__shfl_xor(v.x,m); r.y=__shfl_xor(v.y,m);
  r.z=__shfl_xor(v.z,m); r.w=__shfl_xor(v.w,m); return r;
}
__device__ __forceinline__ float sigf(float x){ return 1.f/(1.f+__expf(-x)); }
__device__ __forceinline__ float tanhf_(float x){ return 2.f/(1.f+__expf(-2.f*x)) - 1.f; }

__device__ __forceinline__ ushort_t f2b(float f){
  union{float f; unsigned u;} v; v.f=f;
  unsigned r = v.u + 0x7FFFu + ((v.u>>16)&1u);
  return (ushort_t)(r>>16);
}
__device__ __forceinline__ float b2f(ushort_t u){
  union{unsigned u; float f;} v; v.u = ((unsigned)u)<<16; return v.f;
}

#define ROWFMA(ACC, AV, WV) \
  ACC[0]=f4fma(AV.x,WV,ACC[0]); ACC[1]=f4fma(AV.y,WV,ACC[1]); \
  ACC[2]=f4fma(AV.z,WV,ACC[2]); ACC[3]=f4fma(AV.w,WV,ACC[3]);

#define MFMA32(A,B,C) __builtin_amdgcn_mfma_f32_32x32x16_bf16(A,B,C,0,0,0)

// ---------------------------------------------------------------------------
// Pack LSTM weights into per-fragment bf16 hi/lo planes.
// B[k][col] for step s; k: 0..63 = x (wih cols 0..63), 64..191 = hx (whh),
// 192..193 = ai (wih cols 64,65), 194 = bias (bih+bhh), 195..207 = 0.
// Fragment layout (32x32x16 B-operand): elem (s,kstep,nt,lane,j) =
//   B[kstep*16 + (lane>>5)*8 + j][nt*32 + (lane&31)]
// ---------------------------------------------------------------------------
__global__ __launch_bounds__(256) void prep_pack(
    const float* __restrict__ wih, const float* __restrict__ whh,
    const float* __restrict__ bih, const float* __restrict__ bhh,
    ushort_t* __restrict__ bph, ushort_t* __restrict__ bpl)
{
  int id = blockIdx.x*256 + threadIdx.x;   // 25*13*16*64 = 332800
  int lane = id & 63;
  int r  = id >> 6;
  int nt = r & 15;
  int r2 = r >> 4;
  int kstep = r2 % 13;
  int s     = r2 / 13;
  int col = nt*32 + (lane&31);
  int k0  = kstep*16 + ((lane>>5)<<3);
  ushort_t hi[8], lo[8];
  #pragma unroll
  for (int j=0;j<8;j++){
    int k = k0+j;
    float w = 0.f;
    if (k < 64)       w = wih[((size_t)s*512+col)*66 + k];
    else if (k < 192) w = whh[((size_t)s*512+col)*128 + (k-64)];
    else if (k < 194) w = wih[((size_t)s*512+col)*66 + 64 + (k-192)];
    else if (k == 194) w = bih[(size_t)s*512+col] + bhh[(size_t)s*512+col];
    ushort_t h_ = f2b(w);
    hi[j] = h_;
    lo[j] = f2b(w - b2f(h_));
  }
  uint4 uh, ul;
  uh.x = hi[0] | ((unsigned)hi[1]<<16); uh.y = hi[2] | ((unsigned)hi[3]<<16);
  uh.z = hi[4] | ((unsigned)hi[5]<<16); uh.w = hi[6] | ((unsigned)hi[7]<<16);
  ul.x = lo[0] | ((unsigned)lo[1]<<16); ul.y = lo[2] | ((unsigned)lo[3]<<16);
  ul.z = lo[4] | ((unsigned)lo[5]<<16); ul.w = lo[6] | ((unsigned)lo[7]<<16);
  *(uint4*)&bph[(size_t)id*8] = uh;
  *(uint4*)&bpl[(size_t)id*8] = ul;
}

// ---------------------------------------------------------------------------
// Graph conv: unchanged from round 3 (known-good, 1726 us).
// ---------------------------------------------------------------------------
__device__ __forceinline__ void reduce_norm(float4 accP[4], float4 accN[4],
    const float* bp, const float* bn, int ks, int dq, float4 kept[4])
{
  #pragma unroll
  for (int j=0;j<4;j++){
    accP[j] = f4add(accP[j], sx4(accP[j],1));
    accN[j] = f4add(accN[j], sx4(accN[j],1));
    kept[j] = (ks&1)? accN[j] : accP[j];
    kept[j] = f4add(kept[j], sx4(kept[j],2));
    kept[j] = f4add(kept[j], sx4(kept[j],4));
  }
  const float* bsel = (ks&1)? bn : bp;
  float4 bb = ((const float4*)bsel)[dq];
  #pragma unroll
  for (int j=0;j<4;j++){
    kept[j].x+=bb.x; kept[j].y+=bb.y; kept[j].z+=bb.z; kept[j].w+=bb.w;
    float ss = kept[j].x*kept[j].x + kept[j].y*kept[j].y
             + kept[j].z*kept[j].z + kept[j].w*kept[j].w;
    ss += __shfl_xor(ss,8); ss += __shfl_xor(ss,16); ss += __shfl_xor(ss,32);
    float sc = 1.f/fmaxf(sqrtf(ss),1e-12f);
    kept[j].x*=sc; kept[j].y*=sc; kept[j].z*=sc; kept[j].w*=sc;
  }
}

__global__ __launch_bounds__(640,2) void graphconv(
    const float* __restrict__ h0, const float* __restrict__ add_info,
    const float* __restrict__ wpb, const float* __restrict__ bpb,
    const float* __restrict__ wnb, const float* __restrict__ bnb,
    const float* __restrict__ wpd, const float* __restrict__ bpd,
    const float* __restrict__ wnd, const float* __restrict__ bnd,
    const int* __restrict__ pos_adj, const int* __restrict__ neg_adj,
    float* __restrict__ xout)
{
  __shared__ __align__(16) float featT[256][FTP];
  __shared__ __align__(16) float wbuf[2][56][WBP];
  __shared__ __align__(16) float h0s[4][PP][32];
  __shared__ __align__(16) float hps[4][PP][32];
  __shared__ __align__(16) float hns[4][PP][32];
  __shared__ float Afp[4][PP][10];
  __shared__ float Afn[4][PP][10];
  __shared__ float degpr[4][PP], degnr[4][PP], degpc[4][PP], degnc[4][PP];

  const int t = threadIdx.x;
  const int rb = t>>6;
  const int dq = (t>>3)&7;
  const int ks = t&7;
  const int agl = t/160;
  const int arem = t%160;
  const int ap = arem>>4;
  const int adq = (arem>>1)&7;
  const int ah = arem&1;
  const long g0 = (long)blockIdx.x*4;

  if (t<400){
    int gg_ = t/100, e = t%100, rr=e/10, cc=e%10;
    float z = (rr==cc)?0.f:1.f;
    Afp[gg_][rr][cc] = z*(float)pos_adj[(g0+gg_)*100 + e];
    Afn[gg_][rr][cc] = z*(float)neg_adj[(g0+gg_)*100 + e];
  }
  if (t<320){
    int gg_ = t/80, pp_ = (t%80)>>3, dd = t&7;
    float4 hv = ((const float4*)(h0 + (g0+gg_)*PP*32))[pp_*8+dd];
    *(float4*)&h0s[gg_][pp_][dd*4] = hv;
    int col = gg_*10+pp_;
    featT[64+dd*4+0][col]=hv.x; featT[64+dd*4+1][col]=hv.y;
    featT[64+dd*4+2][col]=hv.z; featT[64+dd*4+3][col]=hv.w;
  }
  __syncthreads();
  if (t<40){
    int gg_=t/10, pp_=t%10;
    float s0=0,s1=0,s2=0,s3=0;
    for(int q=0;q<10;q++){
      s0+=Afp[gg_][pp_][q]; s1+=Afn[gg_][pp_][q];
      s2+=Afp[gg_][q][pp_]; s3+=Afn[gg_][q][pp_];
    }
    degpr[gg_][pp_]=1.f/fmaxf(s0,1.f);
    degnr[gg_][pp_]=1.f/fmaxf(s1,1.f);
    degpc[gg_][pp_]=1.f/fmaxf(s2,1.f);
    degnc[gg_][pp_]=1.f/fmaxf(s3,1.f);
  }
  __syncthreads();

  {
    float4 bP=make_float4(0,0,0,0), bN=bP;
    #pragma unroll
    for (int qi=0; qi<5; ++qi){
      int q = ah*5+qi;
      float4 hv = *(const float4*)&h0s[agl][q][adq*4];
      bP = f4fma(Afp[agl][ap][q], hv, bP);
      bN = f4fma(Afn[agl][ap][q], hv, bN);
    }
    bP = f4add(bP, sx4(bP,1));
    bN = f4add(bN, sx4(bN,1));
    int col = agl*10+ap;
    if (ah==0){
      float s = degpr[agl][ap];
      featT[adq*4+0][col]=bP.x*s; featT[adq*4+1][col]=bP.y*s;
      featT[adq*4+2][col]=bP.z*s; featT[adq*4+3][col]=bP.w*s;
    } else {
      float s = degnr[agl][ap];
      featT[32+adq*4+0][col]=bN.x*s; featT[32+adq*4+1][col]=bN.y*s;
      featT[32+adq*4+2][col]=bN.z*s; featT[32+adq*4+3][col]=bN.w*s;
    }
  }
  __syncthreads();

  float4 accP[4], accN[4];
  #pragma unroll
  for (int j=0;j<4;j++){ accP[j]=make_float4(0,0,0,0); accN[j]=accP[j]; }

  if (t<512){
    int path=t>>8, rem2=t&255, kk=rem2>>3, dqq=rem2&7;
    const float* ws_ = path? wnb : wpb;
    *(float4*)&wbuf[path][kk][dqq*4] = ((const float4*)(ws_ + kk*32))[dqq];
  }
  __syncthreads();
  #pragma unroll
  for (int i=0;i<4;i++){
    int k = i*8+ks;
    float4 aP = *(const float4*)&featT[k][rb*4];
    float4 aN = *(const float4*)&featT[32+k][rb*4];
    float4 wp = *(const float4*)&wbuf[0][k][dq*4];
    float4 wn = *(const float4*)&wbuf[1][k][dq*4];
    ROWFMA(accP, aP, wp);
    ROWFMA(accN, aN, wn);
  }
  __syncthreads();
  if (t<512){
    int path=t>>8, rem2=t&255, kk=rem2>>3, dqq=rem2&7;
    const float* ws_ = path? wnb : wpb;
    *(float4*)&wbuf[path][kk][dqq*4] = ((const float4*)(ws_ + (32+kk)*32))[dqq];
  }
  __syncthreads();
  #pragma unroll
  for (int i=0;i<4;i++){
    int k = i*8+ks;
    float4 a = *(const float4*)&featT[64+k][rb*4];
    float4 wp = *(const float4*)&wbuf[0][k][dq*4];
    float4 wn = *(const float4*)&wbuf[1][k][dq*4];
    ROWFMA(accP, a, wp);
    ROWFMA(accN, a, wn);
  }

  {
    float4 kept[4];
    reduce_norm(accP, accN, bpb, bnb, ks, dq, kept);
    __syncthreads();
    if (ks==0 || ks==1){
      #pragma unroll
      for (int j=0;j<4;j++){
        int r=rb*4+j;
        float* dst = (ks==0)? &hps[r/10][r%10][dq*4] : &hns[r/10][r%10][dq*4];
        *(float4*)dst = kept[j];
      }
    } else if (ks==2 || ks==3){
      int rowbase = (ks==2)? 192:224;
      #pragma unroll
      for (int j=0;j<4;j++){
        int r=rb*4+j;
        featT[rowbase+dq*4+0][r]=kept[j].x; featT[rowbase+dq*4+1][r]=kept[j].y;
        featT[rowbase+dq*4+2][r]=kept[j].z; featT[rowbase+dq*4+3][r]=kept[j].w;
      }
    }
    __syncthreads();
  }

  #pragma unroll 1
  for (int layer=0; layer<2; ++layer){
    {
      float4 b0=make_float4(0,0,0,0),b1=b0,b2=b0,b3=b0,b4=b0,b5=b0;
      #pragma unroll
      for (int qi=0; qi<5; ++qi){
        int q = ah*5+qi;
        float4 hp = *(const float4*)&hps[agl][q][adq*4];
        float4 hn = *(const float4*)&hns[agl][q][adq*4];
        float apq=Afp[agl][ap][q], anq=Afn[agl][ap][q];
        float apT=Afp[agl][q][ap], anT=Afn[agl][q][ap];
        b0=f4fma(apq,hp,b0); b1=f4fma(anq,hn,b1); b2=f4fma(apq,hn,b2);
        b3=f4fma(anq,hp,b3); b4=f4fma(apT,hp,b4); b5=f4fma(anT,hn,b5);
      }
      b0=f4add(b0,sx4(b0,1)); b1=f4add(b1,sx4(b1,1)); b2=f4add(b2,sx4(b2,1));
      b3=f4add(b3,sx4(b3,1)); b4=f4add(b4,sx4(b4,1)); b5=f4add(b5,sx4(b5,1));
      int col = agl*10+ap;
      if (ah==0){
        float s0=degpr[agl][ap], s1=degnr[agl][ap];
        featT[ adq*4+0][col]=b0.x*s0; featT[ adq*4+1][col]=b0.y*s0;
        featT[ adq*4+2][col]=b0.z*s0; featT[ adq*4+3][col]=b0.w*s0;
        featT[32+adq*4+0][col]=b1.x*s1; featT[32+adq*4+1][col]=b1.y*s1;
        featT[32+adq*4+2][col]=b1.z*s1; featT[32+adq*4+3][col]=b1.w*s1;
        featT[64+adq*4+0][col]=b2.x*s0; featT[64+adq*4+1][col]=b2.y*s0;
        featT[64+adq*4+2][col]=b2.z*s0; featT[64+adq*4+3][col]=b2.w*s0;
      } else {
        float s1=degnr[agl][ap], s2=degpc[agl][ap], s3=degnc[agl][ap];
        featT[ 96+adq*4+0][col]=b3.x*s1; featT[ 96+adq*4+1][col]=b3.y*s1;
        featT[ 96+adq*4+2][col]=b3.z*s1; featT[ 96+adq*4+3][col]=b3.w*s1;
        featT[128+adq*4+0][col]=b4.x*s2; featT[128+adq*4+1][col]=b4.y*s2;
        featT[128+adq*4+2][col]=b4.z*s2; featT[128+adq*4+3][col]=b4.w*s2;
        featT[160+adq*4+0][col]=b5.x*s3; featT[160+adq*4+1][col]=b5.y*s3;
        featT[160+adq*4+2][col]=b5.z*s3; featT[160+adq*4+3][col]=b5.w*s3;
      }
    }
    __syncthreads();

    #pragma unroll
    for (int j=0;j<4;j++){ accP[j]=make_float4(0,0,0,0); accN[j]=accP[j]; }
    const float* wpl = wpd + layer*7168;
    const float* wnl = wnd + layer*7168;
    #pragma unroll
    for (int chunk=0; chunk<4; ++chunk){
      const int c0 = chunk*56;
      for (int idx=t; idx<896; idx+=640){
        int path=idx/448, rem2=idx%448, kk=rem2>>3, dqq=rem2&7;
        const float* ws_ = path? wnl : wpl;
        *(float4*)&wbuf[path][kk][dqq*4] = ((const float4*)(ws_ + (c0+kk)*32))[dqq];
      }
      __syncthreads();
      #pragma unroll
      for (int i=0;i<7;i++){
        int kk = i*8+ks;
        int k = c0 + kk;
        float4 wp = *(const float4*)&wbuf[0][kk][dq*4];
        float4 wn = *(const float4*)&wbuf[1][kk][dq*4];
        if (c0 + i*8 < 192){
          float4 a = *(const float4*)&featT[k][rb*4];
          ROWFMA(accP, a, wp);
          ROWFMA(accN, a, wn);
        } else {
          float4 aP = *(const float4*)&featT[k][rb*4];
          float4 aN = *(const float4*)&featT[k+32][rb*4];
          ROWFMA(accP, aP, wp);
          ROWFMA(accN, aN, wn);
        }
      }
      __syncthreads();
    }

    float4 kept[4];
    reduce_norm(accP, accN, bpd+layer*32, bnd+layer*32, ks, dq, kept);
    if (layer==0){
      if (ks==0 || ks==1){
        #pragma unroll
        for (int j=0;j<4;j++){
          int r=rb*4+j;
          float* dst = (ks==0)? &hps[r/10][r%10][dq*4] : &hns[r/10][r%10][dq*4];
          *(float4*)dst = kept[j];
        }
      } else if (ks==2 || ks==3){
        int rowbase = (ks==2)? 192:224;
        #pragma unroll
        for (int j=0;j<4;j++){
          int r=rb*4+j;
          featT[rowbase+dq*4+0][r]=kept[j].x; featT[rowbase+dq*4+1][r]=kept[j].y;
          featT[rowbase+dq*4+2][r]=kept[j].z; featT[rowbase+dq*4+3][r]=kept[j].w;
        }
      }
      __syncthreads();
    } else {
      if (ks<2){
        #pragma unroll
        for (int j=0;j<4;j++){
          int r=rb*4+j;
          long gid = g0 + r/10;
          int p_ = r%10;
          long gout = gid/25; int rem = (int)(gid%25);
          long orow = ((long)rem*NROW + gout*PP + p_)*XST;
          ((float4*)(xout + orow))[ks*8 + dq] = kept[j];
        }
      }
    }
  }
}

// ---------------------------------------------------------------------------
// Persistent MFMA LSTM: 320 blocks x 512 thr (8 waves), 64 rows/block, 25 steps.
// wave w = t>>6: mt = w>>2 (M-tile of 32 rows), ng = w&3 (col group).
// Wave computes ntiles {ng, ng+4, ng+8, ng+12} = gates i,f,g,o at cols ng*32+..
// acc: f32x16 per gate. cx persistent in VGPR (fp32, never quantized).
// A (LDS, bf16): cols 0..63 x, 64..191 hx(hi), 192..193 ai, 194 = 1.0 (bias), rest 0.
// Alo (LDS, bf16): hx residual, cols 0..127.
// 3 MFMA passes: Ahi*Bhi + Ahi*Blo (all k) + Alo*Bhi (hx ksteps 4..11).
// ---------------------------------------------------------------------------
__global__ __launch_bounds__(512,2) void lstm_persist(
    const float* __restrict__ xbuf, const ushort_t* __restrict__ bph,
    const ushort_t* __restrict__ bpl, const float* __restrict__ hx0,
    const float* __restrict__ cx0, const float* __restrict__ ai,
    float* __restrict__ outp)
{
  __shared__ __align__(16) ushort_t Ahi[64*ASTR];
  __shared__ __align__(16) ushort_t Alo[64*LSTR];

  const int t = threadIdx.x;
  const int lane = t & 63;
  const int w = t >> 6;
  const int mt = w >> 2;
  const int ng = w & 3;
  const long rbase = (long)blockIdx.x * 64;
  const int c = ng*32 + (lane&31);          // hidden index owned

  // ---- one-time init ----
  if (t < 64){
    Ahi[t*ASTR+194] = 0x3F80;               // bf16 1.0 (bias row)
    #pragma unroll
    for (int cc=195; cc<216; ++cc) Ahi[t*ASTR+cc] = 0;
  }
  // ai for step 0
  if (t < 64){
    long R = rbase + t; int g = (int)(R/10), p = (int)(R%10);
    const float* aip = ai + (((size_t)g*5 + 0)*10 + p)*2;
    Ahi[t*ASTR+192] = f2b(aip[0]);
    Ahi[t*ASTR+193] = f2b(aip[1]);
  }
  // x for step 0
  {
    int row = t>>3, c0 = (t&7)*8;
    const float* xr = xbuf + ((size_t)0*NROW + rbase + row)*64 + c0;
    float4 v0 = ((const float4*)xr)[0], v1 = ((const float4*)xr)[1];
    uint4 u;
    u.x = f2b(v0.x) | ((unsigned)f2b(v0.y)<<16);
    u.y = f2b(v0.z) | ((unsigned)f2b(v0.w)<<16);
    u.z = f2b(v1.x) | ((unsigned)f2b(v1.y)<<16);
    u.w = f2b(v1.z) | ((unsigned)f2b(v1.w)<<16);
    *(uint4*)&Ahi[row*ASTR + c0] = u;
  }
  // hx0 (hi+lo) + cx0 into persistent registers
  float cxr[16];
  #pragma unroll
  for (int i=0;i<16;i++){
    int rof = (i&3) + 8*(i>>2) + 4*(lane>>5);
    int lr2 = mt*32 + rof;
    long R = rbase + lr2;
    float h0v = hx0[(size_t)R*HHC + c];
    ushort_t hh = f2b(h0v);
    Ahi[lr2*ASTR + 64 + c] = hh;
    Alo[lr2*LSTR + c]      = f2b(h0v - b2f(hh));
    cxr[i] = cx0[(size_t)R*HHC + c];
  }
  __syncthreads();

  const int lr  = mt*32 + (lane&31);        // A-frag row
  const int kof = (lane>>5)*8;              // A-frag k sub-offset

  #pragma unroll 1
  for (int s=0; s<NSTEP; ++s){
    f32x16 acc0, acc1, acc2, acc3;
    #pragma unroll
    for (int i=0;i<16;i++){ acc0[i]=0.f; acc1[i]=0.f; acc2[i]=0.f; acc3[i]=0.f; }

    #pragma unroll
    for (int kstep=0; kstep<13; ++kstep){
      bf16x8 af = *(const bf16x8*)&Ahi[lr*ASTR + kstep*16 + kof];
      const uint4* bhp = (const uint4*)bph + (((size_t)s*13 + kstep)*16)*64 + lane;
      const uint4* blp = (const uint4*)bpl + (((size_t)s*13 + kstep)*16)*64 + lane;
      bf16x8 bh0 = __builtin_bit_cast(bf16x8, bhp[(ng   )*64]);
      bf16x8 bh1 = __builtin_bit_cast(bf16x8, bhp[(ng+ 4)*64]);
      bf16x8 bh2 = __builtin_bit_cast(bf16x8, bhp[(ng+ 8)*64]);
      bf16x8 bh3 = __builtin_bit_cast(bf16x8, bhp[(ng+12)*64]);
      bf16x8 bl0 = __builtin_bit_cast(bf16x8, blp[(ng   )*64]);
      bf16x8 bl1 = __builtin_bit_cast(bf16x8, blp[(ng+ 4)*64]);
      bf16x8 bl2 = __builtin_bit_cast(bf16x8, blp[(ng+ 8)*64]);
      bf16x8 bl3 = __builtin_bit_cast(bf16x8, blp[(ng+12)*64]);
      acc0 = MFMA32(af, bh0, acc0);  acc1 = MFMA32(af, bh1, acc1);
      acc2 = MFMA32(af, bh2, acc2);  acc3 = MFMA32(af, bh3, acc3);
      acc0 = MFMA32(af, bl0, acc0);  acc1 = MFMA32(af, bl1, acc1);
      acc2 = MFMA32(af, bl2, acc2);  acc3 = MFMA32(af, bl3, acc3);
      if (kstep>=4 && kstep<12){
        bf16x8 al = *(const bf16x8*)&Alo[lr*LSTR + (kstep-4)*16 + kof];
        acc0 = MFMA32(al, bh0, acc0);  acc1 = MFMA32(al, bh1, acc1);
        acc2 = MFMA32(al, bh2, acc2);  acc3 = MFMA32(al, bh3, acc3);
      }
    }
    __syncthreads();   // done reading A for this step

    // cell update + stage next step
    #pragma unroll
    for (int i=0;i<16;i++){
      int rof = (i&3) + 8*(i>>2) + 4*(lane>>5);
      int lr2 = mt*32 + rof;
      long R = rbase + lr2;
      float ig = sigf(acc0[i]), fg = sigf(acc1[i]);
      float gg = tanhf_(acc2[i]), og = sigf(acc3[i]);
      float cn = fg*cxr[i] + ig*gg;
      cxr[i] = cn;
      float h = og*tanhf_(cn);
      if (s == NSTEP-1){
        outp[(size_t)R*HHC + c] = h;
      } else {
        ushort_t hh = f2b(h);
        Ahi[lr2*ASTR + 64 + c] = hh;
        Alo[lr2*LSTR + c]      = f2b(h - b2f(hh));
      }
    }
    if (s < NSTEP-1){
      // x for step s+1
      int row = t>>3, c0 = (t&7)*8;
      const float* xr = xbuf + ((size_t)(s+1)*NROW + rbase + row)*64 + c0;
      float4 v0 = ((const float4*)xr)[0], v1 = ((const float4*)xr)[1];
      uint4 u;
      u.x = f2b(v0.x) | ((unsigned)f2b(v0.y)<<16);
      u.y = f2b(v0.z) | ((unsigned)f2b(v0.w)<<16);
      u.z = f2b(v1.x) | ((unsigned)f2b(v1.y)<<16);
      u.w = f2b(v1.z) | ((unsigned)f2b(v1.w)<<16);
      *(uint4*)&Ahi[row*ASTR + c0] = u;
      if (((s+1)%5)==0 && t<64){
        long R = rbase + t; int g = (int)(R/10), p = (int)(R%10);
        const float* aip = ai + (((size_t)g*5 + (s+1)/5)*10 + p)*2;
        Ahi[t*ASTR+192] = f2b(aip[0]);
        Ahi[t*ASTR+193] = f2b(aip[1]);
      }
      __syncthreads(); // staged A visible before next GEMM
    }
  }
}

// ---------------------------------------------------------------------------
extern "C" void kernel_launch(void* const* d_in, const int* in_sizes, int n_in,
                              void* d_out, int out_size, void* d_ws, size_t ws_size,
                              hipStream_t stream)
{
  const float* h0  = (const float*)d_in[0];
  const float* ai  = (const float*)d_in[1];
  const float* wpb = (const float*)d_in[2];
  const float* bpb = (const float*)d_in[3];
  const float* wnb = (const float*)d_in[4];
  const float* bnb = (const float*)d_in[5];
  const float* wpd = (const float*)d_in[6];
  const float* bpd = (const float*)d_in[7];
  const float* wnd = (const float*)d_in[8];
  const float* bnd = (const float*)d_in[9];
  const float* wih = (const float*)d_in[10];
  const float* whh = (const float*)d_in[11];
  const float* bih = (const float*)d_in[12];
  const float* bhh = (const float*)d_in[13];
  const float* hx0 = (const float*)d_in[14];
  const float* cx0 = (const float*)d_in[15];
  const int* padj  = (const int*)d_in[16];
  const int* nadj  = (const int*)d_in[17];
  float* out = (float*)d_out;

  float* ws   = (float*)d_ws;
  float* xbuf = ws;                                       // 25*20480*64 f32
  ushort_t* bph = (ushort_t*)(xbuf + (size_t)NSTEP*NROW*XST);   // 2,662,400 u16
  ushort_t* bpl = bph + (size_t)NSTEP*13*16*64*8;               // 2,662,400 u16

  prep_pack<<<1300,256,0,stream>>>(wih,whh,bih,bhh,bph,bpl);
  graphconv<<<12800,640,0,stream>>>(h0,ai,wpb,bpb,wnb,bnb,wpd,bpd,wnd,bnd,padj,nadj,xbuf);
  lstm_persist<<<320,512,0,stream>>>(xbuf,bph,bpl,hx0,cx0,ai,out);
}

// Round 6
// 1302.666 us; speedup vs baseline: 4.4085x; 1.8231x over previous
//
#include <hip/hip_runtime.h>
#include <hip/hip_bf16.h>

#define GG 2048
#define PP 10
#define HHC 128
#define NSTEP 25
#define NROW (GG*PP)      // 20480
#define ASTR 216          // lstm Ahi stride (bf16)
#define LSTR 136          // lstm Alo stride
#define GPB 8             // graphs per graphconv block
#define AST 232           // graphconv A stride (bf16 elems)
#define A2ST 40

typedef __attribute__((ext_vector_type(8))) short bf16x8;
typedef __attribute__((ext_vector_type(16))) float f32x16;
typedef unsigned short ushort_t;

__device__ __forceinline__ float4 f4fma(float s, const float4 w, float4 a){
  a.x = fmaf(s, w.x, a.x); a.y = fmaf(s, w.y, a.y);
  a.z = fmaf(s, w.z, a.z); a.w = fmaf(s, w.w, a.w);
  return a;
}
__device__ __forceinline__ float4 f4s(float4 a, float s){
  a.x*=s; a.y*=s; a.z*=s; a.w*=s; return a;
}
__device__ __forceinline__ float sigf(float x){ return 1.f/(1.f+__expf(-x)); }
__device__ __forceinline__ float tanhf_(float x){ return 2.f/(1.f+__expf(-2.f*x)) - 1.f; }

__device__ __forceinline__ ushort_t f2b(float f){
  union{float f; unsigned u;} v; v.f=f;
  unsigned r = v.u + 0x7FFFu + ((v.u>>16)&1u);
  return (ushort_t)(r>>16);
}
__device__ __forceinline__ float b2f(ushort_t u){
  union{unsigned u; float f;} v; v.u = ((unsigned)u)<<16; return v.f;
}
__device__ __forceinline__ uint4 packh(float4 a, float4 b){
  uint4 h;
  h.x = f2b(a.x)|((unsigned)f2b(a.y)<<16); h.y = f2b(a.z)|((unsigned)f2b(a.w)<<16);
  h.z = f2b(b.x)|((unsigned)f2b(b.y)<<16); h.w = f2b(b.z)|((unsigned)f2b(b.w)<<16);
  return h;
}
__device__ __forceinline__ void unp8(bf16x8 v, float4& a, float4& b){
  const unsigned* u = (const unsigned*)&v;
  union{unsigned q; float f;} c;
  c.q = u[0]<<16;          a.x=c.f;
  c.q = u[0]&0xffff0000u;  a.y=c.f;
  c.q = u[1]<<16;          a.z=c.f;
  c.q = u[1]&0xffff0000u;  a.w=c.f;
  c.q = u[2]<<16;          b.x=c.f;
  c.q = u[2]&0xffff0000u;  b.y=c.f;
  c.q = u[3]<<16;          b.z=c.f;
  c.q = u[3]&0xffff0000u;  b.w=c.f;
}

#define MFMA32(A,B,C) __builtin_amdgcn_mfma_f32_32x32x16_bf16(A,B,C,0,0,0)
#define BC8(u) __builtin_bit_cast(bf16x8, u)

// ---------------------------------------------------------------------------
// LSTM weight pack (unchanged from R5, proven): B[k][col] per step.
// k: 0..63 x, 64..191 hx, 192..193 ai, 194 bias, rest 0.
// frag elem (s,kstep,nt,lane,j) = B[kstep*16+(lane>>5)*8+j][nt*32+(lane&31)]
// ---------------------------------------------------------------------------
__global__ __launch_bounds__(256) void prep_pack(
    const float* __restrict__ wih, const float* __restrict__ whh,
    const float* __restrict__ bih, const float* __restrict__ bhh,
    ushort_t* __restrict__ bph, ushort_t* __restrict__ bpl)
{
  int id = blockIdx.x*256 + threadIdx.x;   // 25*13*16*64 = 332800
  int lane = id & 63;
  int r  = id >> 6;
  int nt = r & 15;
  int r2 = r >> 4;
  int kstep = r2 % 13;
  int s     = r2 / 13;
  int col = nt*32 + (lane&31);
  int k0  = kstep*16 + ((lane>>5)<<3);
  ushort_t hi[8], lo[8];
  #pragma unroll
  for (int j=0;j<8;j++){
    int k = k0+j;
    float w = 0.f;
    if (k < 64)       w = wih[((size_t)s*512+col)*66 + k];
    else if (k < 192) w = whh[((size_t)s*512+col)*128 + (k-64)];
    else if (k < 194) w = wih[((size_t)s*512+col)*66 + 64 + (k-192)];
    else if (k == 194) w = bih[(size_t)s*512+col] + bhh[(size_t)s*512+col];
    ushort_t h_ = f2b(w);
    hi[j] = h_;
    lo[j] = f2b(w - b2f(h_));
  }
  uint4 uh, ul;
  uh.x = hi[0] | ((unsigned)hi[1]<<16); uh.y = hi[2] | ((unsigned)hi[3]<<16);
  uh.z = hi[4] | ((unsigned)hi[5]<<16); uh.w = hi[6] | ((unsigned)hi[7]<<16);
  ul.x = lo[0] | ((unsigned)lo[1]<<16); ul.y = lo[2] | ((unsigned)lo[3]<<16);
  ul.z = lo[4] | ((unsigned)lo[5]<<16); ul.w = lo[6] | ((unsigned)lo[7]<<16);
  *(uint4*)&bph[(size_t)id*8] = uh;
  *(uint4*)&bpl[(size_t)id*8] = ul;
}

// ---------------------------------------------------------------------------
// Graphconv weight pack: 32 slots (0..3 base, 4+layer*14+kstep deep),
// gw[((slot*2+path)*2+hl)*512 + lane*8 + j] = frag elem.
// base: B[k][col] = w{p,n}b[k*32+col] (k<64). deep: w{p,n}d[(layer*224+k)*32+col]
// ---------------------------------------------------------------------------
__global__ __launch_bounds__(256) void prep_gw(
    const float* __restrict__ wpb, const float* __restrict__ wnb,
    const float* __restrict__ wpd, const float* __restrict__ wnd,
    ushort_t* __restrict__ gw)
{
  int id = blockIdx.x*256 + threadIdx.x;   // 8192
  int lane = id & 63;
  int r = id >> 6;                          // 0..127
  int hl = r & 1, path = (r>>1)&1, slot = r>>2;
  int col = lane & 31;
  int kb = (lane>>5)*8;
  ushort_t outv[8];
  #pragma unroll
  for (int j=0;j<8;j++){
    float wv;
    if (slot < 4){
      int k = slot*16 + kb + j;
      wv = (path? wnb : wpb)[k*32 + col];
    } else {
      int sl = slot-4; int layer = sl/14, kstep = sl%14;
      int k = kstep*16 + kb + j;
      wv = (path? wnd : wpd)[((size_t)layer*224 + k)*32 + col];
    }
    ushort_t h = f2b(wv);
    outv[j] = hl ? f2b(wv - b2f(h)) : h;
  }
  uint4 u;
  u.x = outv[0]|((unsigned)outv[1]<<16); u.y = outv[2]|((unsigned)outv[3]<<16);
  u.z = outv[4]|((unsigned)outv[5]<<16); u.w = outv[6]|((unsigned)outv[7]<<16);
  *(uint4*)&gw[(size_t)id*8] = u;
}

// ---------------------------------------------------------------------------
// MFMA graphconv: 8 graphs/block (rows 0..79 real, 80..95 pad), 384 thr = 6 waves.
// wave wv: path = wv&1, Mt = wv>>1 (M-tile of 32 rows).
// A  [96][AST]  bf16: deep cols 0..191 = 6 agg blocks (ref order), 192..223 self h_pos
//               base: 0..31 aggP, 32..63 h0(hi)
// A2 [96][A2ST] bf16: deep self h_neg; base aggN
// A3 [96][A2ST] bf16: h0 lo (base only)
// Weights: bf16 hi+lo fragments from gw (global, L2-resident) -> 2 MFMA passes
// (+1 A-lo pass for h0). Aggregations + L2-norm on fp32 VALU.
// ---------------------------------------------------------------------------
__global__ __launch_bounds__(384) void graphconv(
    const float* __restrict__ h0,
    const float* __restrict__ bpb, const float* __restrict__ bnb,
    const float* __restrict__ bpd, const float* __restrict__ bnd,
    const ushort_t* __restrict__ gw,
    const int* __restrict__ pos_adj, const int* __restrict__ neg_adj,
    ushort_t* __restrict__ xout)
{
  __shared__ __align__(16) ushort_t A [96*AST];
  __shared__ __align__(16) ushort_t A2[96*A2ST];
  __shared__ __align__(16) ushort_t A3[96*A2ST];
  __shared__ float Afp[GPB][10][10], Afn[GPB][10][10];
  __shared__ float dgrp[GPB][10], dgrn[GPB][10], dgcp[GPB][10], dgcn[GPB][10];

  const int t = threadIdx.x;
  const int lane = t & 63;
  const int wv = t >> 6;
  const int path = wv & 1;
  const int Mt = wv >> 1;
  const long g0 = (long)blockIdx.x * GPB;
  const int arow = Mt*32 + (lane&31);
  const int kof = (lane>>5)*8;
  const int col = lane & 31;
  const uint4* gw4 = (const uint4*)gw;

  // ---- adjacency (zero diag) ----
  for (int i=t; i<800; i+=384){
    int g_=i/100, e=i%100, rr=e/10, cc=e%10;
    float z = (rr==cc)?0.f:1.f;
    Afp[g_][rr][cc] = z*(float)pos_adj[(g0+g_)*100+e];
    Afn[g_][rr][cc] = z*(float)neg_adj[(g0+g_)*100+e];
  }
  // ---- h0 -> A hi (cols 32..63) + A3 lo ----
  if (t < 320){
    int row = t>>2, seg = t&3;
    const float* hr = h0 + (size_t)g0*320 + (size_t)row*32 + seg*8;
    float4 v0 = ((const float4*)hr)[0], v1 = ((const float4*)hr)[1];
    ushort_t h_[8], l_[8];
    float vv[8] = {v0.x,v0.y,v0.z,v0.w,v1.x,v1.y,v1.z,v1.w};
    #pragma unroll
    for (int j=0;j<8;j++){ h_[j]=f2b(vv[j]); l_[j]=f2b(vv[j]-b2f(h_[j])); }
    uint4 uh, ul;
    uh.x=h_[0]|((unsigned)h_[1]<<16); uh.y=h_[2]|((unsigned)h_[3]<<16);
    uh.z=h_[4]|((unsigned)h_[5]<<16); uh.w=h_[6]|((unsigned)h_[7]<<16);
    ul.x=l_[0]|((unsigned)l_[1]<<16); ul.y=l_[2]|((unsigned)l_[3]<<16);
    ul.z=l_[4]|((unsigned)l_[5]<<16); ul.w=l_[6]|((unsigned)l_[7]<<16);
    *(uint4*)&A [row*AST  + 32 + seg*8] = uh;
    *(uint4*)&A3[row*A2ST +      seg*8] = ul;
  }
  // ---- zero pad rows 80..95 ----
  for (int i=t; i<16*116; i+=384) ((unsigned*)A)[(80+i/116)*116 + (i%116)] = 0u;
  for (int i=t; i<16*20; i+=384){
    ((unsigned*)A2)[(80+i/20)*20 + (i%20)] = 0u;
    ((unsigned*)A3)[(80+i/20)*20 + (i%20)] = 0u;
  }
  __syncthreads();
  // ---- degrees ----
  if (t < 80){
    int g_=t/10, p_=t%10;
    float s0=0,s1=0,s2=0,s3=0;
    for (int q=0;q<10;q++){
      s0+=Afp[g_][p_][q]; s1+=Afn[g_][p_][q];
      s2+=Afp[g_][q][p_]; s3+=Afn[g_][q][p_];
    }
    dgrp[g_][p_]=1.f/fmaxf(s0,1.f); dgrn[g_][p_]=1.f/fmaxf(s1,1.f);
    dgcp[g_][p_]=1.f/fmaxf(s2,1.f); dgcn[g_][p_]=1.f/fmaxf(s3,1.f);
  }
  __syncthreads();

  // ---- base aggregation (fp32 from global h0) ----
  if (t < 320){
    int gp=t>>2, cq=t&3, g_=gp/10, p_=gp%10;
    float4 aP0={0,0,0,0}, aP1=aP0, aN0=aP0, aN1=aP0;
    const float* hb = h0 + (size_t)(g0+g_)*320 + cq*8;
    #pragma unroll 1
    for (int q=0;q<10;q++){
      const float* hq = hb + q*32;
      float4 u0=((const float4*)hq)[0], u1=((const float4*)hq)[1];
      float ap=Afp[g_][p_][q], an=Afn[g_][p_][q];
      aP0=f4fma(ap,u0,aP0); aP1=f4fma(ap,u1,aP1);
      aN0=f4fma(an,u0,aN0); aN1=f4fma(an,u1,aN1);
    }
    float sp=dgrp[g_][p_], sn=dgrn[g_][p_];
    *(uint4*)&A [gp*AST  + cq*8] = packh(f4s(aP0,sp), f4s(aP1,sp));
    *(uint4*)&A2[gp*A2ST + cq*8] = packh(f4s(aN0,sn), f4s(aN1,sn));
  }
  __syncthreads();

  // ---- base matmul: K=64; pos: A k0..3 ; neg: A2 k0..1 + A k2..3 ; h0lo pass ----
  {
    f32x16 acc;
    #pragma unroll
    for (int i=0;i<16;i++) acc[i]=0.f;
    #pragma unroll
    for (int ks2=0; ks2<2; ++ks2){
      uint4 bh = gw4[((ks2*2+path)*2+0)*64 + lane];
      uint4 bl = gw4[((ks2*2+path)*2+1)*64 + lane];
      bf16x8 af = path ? *(const bf16x8*)&A2[arow*A2ST + ks2*16 + kof]
                       : *(const bf16x8*)&A [arow*AST  + ks2*16 + kof];
      acc = MFMA32(af, BC8(bh), acc);
      acc = MFMA32(af, BC8(bl), acc);
    }
    #pragma unroll
    for (int ks2=2; ks2<4; ++ks2){
      uint4 bh = gw4[((ks2*2+path)*2+0)*64 + lane];
      uint4 bl = gw4[((ks2*2+path)*2+1)*64 + lane];
      bf16x8 af = *(const bf16x8*)&A [arow*AST  + ks2*16 + kof];
      bf16x8 al = *(const bf16x8*)&A3[arow*A2ST + (ks2-2)*16 + kof];
      acc = MFMA32(af, BC8(bh), acc);
      acc = MFMA32(af, BC8(bl), acc);
      acc = MFMA32(al, BC8(bh), acc);
    }
    // bias + L2 norm + quantize
    float bcol = path ? bnb[col] : bpb[col];
    ushort_t qv[16];
    #pragma unroll
    for (int i=0;i<16;i++){
      float v = acc[i] + bcol;
      float ss = v*v;
      ss += __shfl_xor(ss,1); ss += __shfl_xor(ss,2); ss += __shfl_xor(ss,4);
      ss += __shfl_xor(ss,8); ss += __shfl_xor(ss,16);
      float sc = 1.f/fmaxf(sqrtf(ss),1e-12f);
      qv[i] = f2b(v*sc);
    }
    __syncthreads();           // all base MFMA reads (A2 aggN!) done
    #pragma unroll
    for (int i=0;i<16;i++){
      int row = Mt*32 + (i&3) + 8*(i>>2) + 4*(lane>>5);
      if (path==0) A [row*AST  + 192 + col] = qv[i];
      else         A2[row*A2ST +       col] = qv[i];
    }
  }
  __syncthreads();

  // ---- deep layers ----
  #pragma unroll 1
  for (int layer=0; layer<2; ++layer){
    // aggregation from bf16 self blocks
    if (t < 320){
      int gp=t>>2, cq=t&3, g_=gp/10, p_=gp%10;
      float4 c0a={0,0,0,0},c0b=c0a,c1a=c0a,c1b=c0a,c2a=c0a,c2b=c0a;
      float4 c3a=c0a,c3b=c0a,c4a=c0a,c4b=c0a,c5a=c0a,c5b=c0a;
      #pragma unroll 1
      for (int q=0;q<10;q++){
        int rq = g_*10+q;
        bf16x8 hp8 = *(const bf16x8*)&A [rq*AST  + 192 + cq*8];
        bf16x8 hn8 = *(const bf16x8*)&A2[rq*A2ST +       cq*8];
        float4 hpa,hpb,hna,hnb;
        unp8(hp8,hpa,hpb); unp8(hn8,hna,hnb);
        float ap=Afp[g_][p_][q], an=Afn[g_][p_][q];
        float apT=Afp[g_][q][p_], anT=Afn[g_][q][p_];
        c0a=f4fma(ap ,hpa,c0a); c0b=f4fma(ap ,hpb,c0b);
        c1a=f4fma(an ,hna,c1a); c1b=f4fma(an ,hnb,c1b);
        c2a=f4fma(ap ,hna,c2a); c2b=f4fma(ap ,hnb,c2b);
        c3a=f4fma(an ,hpa,c3a); c3b=f4fma(an ,hpb,c3b);
        c4a=f4fma(apT,hpa,c4a); c4b=f4fma(apT,hpb,c4b);
        c5a=f4fma(anT,hna,c5a); c5b=f4fma(anT,hnb,c5b);
      }
      float srp=dgrp[g_][p_], srn=dgrn[g_][p_], scp=dgcp[g_][p_], scn=dgcn[g_][p_];
      *(uint4*)&A[gp*AST +   0 + cq*8] = packh(f4s(c0a,srp), f4s(c0b,srp));
      *(uint4*)&A[gp*AST +  32 + cq*8] = packh(f4s(c1a,srn), f4s(c1b,srn));
      *(uint4*)&A[gp*AST +  64 + cq*8] = packh(f4s(c2a,srp), f4s(c2b,srp));
      *(uint4*)&A[gp*AST +  96 + cq*8] = packh(f4s(c3a,srn), f4s(c3b,srn));
      *(uint4*)&A[gp*AST + 128 + cq*8] = packh(f4s(c4a,scp), f4s(c4b,scp));
      *(uint4*)&A[gp*AST + 160 + cq*8] = packh(f4s(c5a,scn), f4s(c5b,scn));
    }
    __syncthreads();

    // matmul K=224 (14 ksteps), hi+lo weight passes
    f32x16 acc;
    #pragma unroll
    for (int i=0;i<16;i++) acc[i]=0.f;
    const int slot0 = 4 + layer*14;
    #pragma unroll
    for (int kstep=0; kstep<14; ++kstep){
      uint4 bh = gw4[(((slot0+kstep)*2+path)*2+0)*64 + lane];
      uint4 bl = gw4[(((slot0+kstep)*2+path)*2+1)*64 + lane];
      bf16x8 af;
      if (kstep<12 || path==0) af = *(const bf16x8*)&A [arow*AST  + kstep*16 + kof];
      else                     af = *(const bf16x8*)&A2[arow*A2ST + (kstep-12)*16 + kof];
      acc = MFMA32(af, BC8(bh), acc);
      acc = MFMA32(af, BC8(bl), acc);
    }
    float bcol = (path ? bnd : bpd)[layer*32 + col];
    ushort_t qv[16];
    #pragma unroll
    for (int i=0;i<16;i++){
      float v = acc[i] + bcol;
      float ss = v*v;
      ss += __shfl_xor(ss,1); ss += __shfl_xor(ss,2); ss += __shfl_xor(ss,4);
      ss += __shfl_xor(ss,8); ss += __shfl_xor(ss,16);
      float sc = 1.f/fmaxf(sqrtf(ss),1e-12f);
      qv[i] = f2b(v*sc);
    }
    if (layer==0){
      __syncthreads();       // all MFMA reads of self regions done
      #pragma unroll
      for (int i=0;i<16;i++){
        int row = Mt*32 + (i&3) + 8*(i>>2) + 4*(lane>>5);
        if (path==0) A [row*AST  + 192 + col] = qv[i];
        else         A2[row*A2ST +       col] = qv[i];
      }
      __syncthreads();
    } else {
      // final: write x rows to global bf16 (pos cols 0..31, neg 32..63)
      #pragma unroll
      for (int i=0;i<16;i++){
        int row = Mt*32 + (i&3) + 8*(i>>2) + 4*(lane>>5);
        if (row < 80){
          long gid = g0 + row/10;
          int p_ = row%10;
          size_t off = ((size_t)(gid%25)*NROW + (size_t)(gid/25)*10 + p_)*64
                     + path*32 + col;
          xout[off] = qv[i];
        }
      }
    }
  }
}

// ---------------------------------------------------------------------------
// Persistent MFMA LSTM: 320 blocks x 256 thr (4 waves), 64 rows/block, 25 steps.
// wave = ng (col group); each wave: 2 M-tiles x 4 gate-tiles (nt = ng+g*4).
// B-fragments loaded once per (kstep,gate), shared across both M-tiles.
// cx persistent fp32 in VGPR; hx round-trips LDS as bf16 hi+lo; x read as bf16.
// ---------------------------------------------------------------------------
__global__ __launch_bounds__(256,2) void lstm_persist(
    const ushort_t* __restrict__ xbuf, const ushort_t* __restrict__ bph,
    const ushort_t* __restrict__ bpl, const float* __restrict__ hx0,
    const float* __restrict__ cx0, const float* __restrict__ ai,
    float* __restrict__ outp)
{
  __shared__ __align__(16) ushort_t Ahi[64*ASTR];
  __shared__ __align__(16) ushort_t Alo[64*LSTR];

  const int t = threadIdx.x;
  const int lane = t & 63;
  const int ng = t >> 6;                    // 0..3
  const long rbase = (long)blockIdx.x * 64;
  const int c = ng*32 + (lane&31);          // hidden col owned
  const int kof = (lane>>5)*8;

  // ---- one-time init ----
  if (t < 64){
    Ahi[t*ASTR+194] = 0x3F80;               // bf16 1.0 (bias row)
    #pragma unroll
    for (int cc=195; cc<216; ++cc) Ahi[t*ASTR+cc] = 0;
    long R = rbase + t; int g = (int)(R/10), p = (int)(R%10);
    const float* aip = ai + (((size_t)g*5 + 0)*10 + p)*2;
    Ahi[t*ASTR+192] = f2b(aip[0]);
    Ahi[t*ASTR+193] = f2b(aip[1]);
  }
  // x step 0 (bf16 direct copy)
  for (int idx=t; idx<512; idx+=256){
    int row = idx>>3, c0 = (idx&7)*8;
    *(uint4*)&Ahi[row*ASTR + c0] =
        *(const uint4*)&xbuf[((size_t)0*NROW + rbase + row)*64 + c0];
  }
  // hx0 (hi+lo) + cx0
  float cxr[2][16];
  #pragma unroll
  for (int mt=0; mt<2; ++mt){
    #pragma unroll
    for (int i=0;i<16;i++){
      int rof = (i&3) + 8*(i>>2) + 4*(lane>>5);
      int lr2 = mt*32 + rof;
      long R = rbase + lr2;
      float h0v = hx0[(size_t)R*HHC + c];
      ushort_t hh = f2b(h0v);
      Ahi[lr2*ASTR + 64 + c] = hh;
      Alo[lr2*LSTR + c]      = f2b(h0v - b2f(hh));
      cxr[mt][i] = cx0[(size_t)R*HHC + c];
    }
  }
  __syncthreads();

  #pragma unroll 1
  for (int s=0; s<NSTEP; ++s){
    f32x16 acc[2][4];
    #pragma unroll
    for (int mt=0;mt<2;++mt)
      #pragma unroll
      for (int g=0;g<4;++g)
        #pragma unroll
        for (int i=0;i<16;i++) acc[mt][g][i]=0.f;

    #pragma unroll
    for (int kstep=0; kstep<13; ++kstep){
      const uint4* bhp = (const uint4*)bph + ((size_t)s*13 + kstep)*1024 + lane;
      const uint4* blp = (const uint4*)bpl + ((size_t)s*13 + kstep)*1024 + lane;
      bf16x8 af0 = *(const bf16x8*)&Ahi[( 0+(lane&31))*ASTR + kstep*16 + kof];
      bf16x8 af1 = *(const bf16x8*)&Ahi[(32+(lane&31))*ASTR + kstep*16 + kof];
      if (kstep>=4 && kstep<12){
        bf16x8 al0 = *(const bf16x8*)&Alo[( 0+(lane&31))*LSTR + (kstep-4)*16 + kof];
        bf16x8 al1 = *(const bf16x8*)&Alo[(32+(lane&31))*LSTR + (kstep-4)*16 + kof];
        #pragma unroll
        for (int g=0;g<4;++g){
          uint4 bh = bhp[(ng+g*4)*64];
          uint4 bl = blp[(ng+g*4)*64];
          acc[0][g] = MFMA32(af0, BC8(bh), acc[0][g]);
          acc[1][g] = MFMA32(af1, BC8(bh), acc[1][g]);
          acc[0][g] = MFMA32(af0, BC8(bl), acc[0][g]);
          acc[1][g] = MFMA32(af1, BC8(bl), acc[1][g]);
          acc[0][g] = MFMA32(al0, BC8(bh), acc[0][g]);
          acc[1][g] = MFMA32(al1, BC8(bh), acc[1][g]);
        }
      } else {
        #pragma unroll
        for (int g=0;g<4;++g){
          uint4 bh = bhp[(ng+g*4)*64];
          uint4 bl = blp[(ng+g*4)*64];
          acc[0][g] = MFMA32(af0, BC8(bh), acc[0][g]);
          acc[1][g] = MFMA32(af1, BC8(bh), acc[1][g]);
          acc[0][g] = MFMA32(af0, BC8(bl), acc[0][g]);
          acc[1][g] = MFMA32(af1, BC8(bl), acc[1][g]);
        }
      }
    }
    __syncthreads();   // done reading A for this step

    // cell update + stage next step
    #pragma unroll
    for (int mt=0; mt<2; ++mt){
      #pragma unroll
      for (int i=0;i<16;i++){
        int rof = (i&3) + 8*(i>>2) + 4*(lane>>5);
        int lr2 = mt*32 + rof;
        long R = rbase + lr2;
        float ig = sigf(acc[mt][0][i]), fg = sigf(acc[mt][1][i]);
        float gg = tanhf_(acc[mt][2][i]), og = sigf(acc[mt][3][i]);
        float cn = fg*cxr[mt][i] + ig*gg;
        cxr[mt][i] = cn;
        float h = og*tanhf_(cn);
        if (s == NSTEP-1){
          outp[(size_t)R*HHC + c] = h;
        } else {
          ushort_t hh = f2b(h);
          Ahi[lr2*ASTR + 64 + c] = hh;
          Alo[lr2*LSTR + c]      = f2b(h - b2f(hh));
        }
      }
    }
    if (s < NSTEP-1){
      for (int idx=t; idx<512; idx+=256){
        int row = idx>>3, c0 = (idx&7)*8;
        *(uint4*)&Ahi[row*ASTR + c0] =
            *(const uint4*)&xbuf[((size_t)(s+1)*NROW + rbase + row)*64 + c0];
      }
      if (((s+1)%5)==0 && t<64){
        long R = rbase + t; int g = (int)(R/10), p = (int)(R%10);
        const float* aip = ai + (((size_t)g*5 + (s+1)/5)*10 + p)*2;
        Ahi[t*ASTR+192] = f2b(aip[0]);
        Ahi[t*ASTR+193] = f2b(aip[1]);
      }
      __syncthreads();
    }
  }
}

// ---------------------------------------------------------------------------
extern "C" void kernel_launch(void* const* d_in, const int* in_sizes, int n_in,
                              void* d_out, int out_size, void* d_ws, size_t ws_size,
                              hipStream_t stream)
{
  const float* h0  = (const float*)d_in[0];
  const float* ai  = (const float*)d_in[1];
  const float* wpb = (const float*)d_in[2];
  const float* bpb = (const float*)d_in[3];
  const float* wnb = (const float*)d_in[4];
  const float* bnb = (const float*)d_in[5];
  const float* wpd = (const float*)d_in[6];
  const float* bpd = (const float*)d_in[7];
  const float* wnd = (const float*)d_in[8];
  const float* bnd = (const float*)d_in[9];
  const float* wih = (const float*)d_in[10];
  const float* whh = (const float*)d_in[11];
  const float* bih = (const float*)d_in[12];
  const float* bhh = (const float*)d_in[13];
  const float* hx0 = (const float*)d_in[14];
  const float* cx0 = (const float*)d_in[15];
  const int* padj  = (const int*)d_in[16];
  const int* nadj  = (const int*)d_in[17];
  float* out = (float*)d_out;

  ushort_t* xbuf16 = (ushort_t*)d_ws;                        // 25*20480*64 u16
  ushort_t* bph = xbuf16 + (size_t)NSTEP*NROW*64;            // 2,662,400 u16
  ushort_t* bpl = bph + (size_t)NSTEP*13*16*64*8;            // 2,662,400 u16
  ushort_t* gw  = bpl + (size_t)NSTEP*13*16*64*8;            // 65,536 u16

  prep_pack<<<1300,256,0,stream>>>(wih,whh,bih,bhh,bph,bpl);
  prep_gw<<<32,256,0,stream>>>(wpb,wnb,wpd,wnd,gw);
  graphconv<<<6400,384,0,stream>>>(h0,bpb,bnb,bpd,bnd,gw,padj,nadj,xbuf16);
  lstm_persist<<<320,256,0,stream>>>(xbuf16,bph,bpl,hx0,cx0,ai,out);
}

// Round 7
// 1062.047 us; speedup vs baseline: 5.4073x; 1.2266x over previous
//
#include <hip/hip_runtime.h>
#include <hip/hip_bf16.h>

#define GG 2048
#define PP 10
#define HHC 128
#define NSTEP 25
#define NROW (GG*PP)      // 20480
#define ASTR 216          // lstm Ahi stride (bf16)
#define LSTR 136          // lstm Alo stride
#define GPB 8             // graphs per graphconv block
#define AST 232           // graphconv A stride (bf16 elems)
#define A2ST 40
#define LROWS 80          // real rows per lstm block (256 blocks * 80 = 20480)
#define LB 768            // lstm threads per block

typedef __attribute__((ext_vector_type(8))) short bf16x8;
typedef __attribute__((ext_vector_type(16))) float f32x16;
typedef unsigned short ushort_t;

__device__ __forceinline__ float4 f4fma(float s, const float4 w, float4 a){
  a.x = fmaf(s, w.x, a.x); a.y = fmaf(s, w.y, a.y);
  a.z = fmaf(s, w.z, a.z); a.w = fmaf(s, w.w, a.w);
  return a;
}
__device__ __forceinline__ float4 f4s(float4 a, float s){
  a.x*=s; a.y*=s; a.z*=s; a.w*=s; return a;
}
__device__ __forceinline__ float sigf(float x){ return 1.f/(1.f+__expf(-x)); }
__device__ __forceinline__ float tanhf_(float x){ return 2.f/(1.f+__expf(-2.f*x)) - 1.f; }

__device__ __forceinline__ ushort_t f2b(float f){
  union{float f; unsigned u;} v; v.f=f;
  unsigned r = v.u + 0x7FFFu + ((v.u>>16)&1u);
  return (ushort_t)(r>>16);
}
__device__ __forceinline__ float b2f(ushort_t u){
  union{unsigned u; float f;} v; v.u = ((unsigned)u)<<16; return v.f;
}
__device__ __forceinline__ uint4 packh(float4 a, float4 b){
  uint4 h;
  h.x = f2b(a.x)|((unsigned)f2b(a.y)<<16); h.y = f2b(a.z)|((unsigned)f2b(a.w)<<16);
  h.z = f2b(b.x)|((unsigned)f2b(b.y)<<16); h.w = f2b(b.z)|((unsigned)f2b(b.w)<<16);
  return h;
}
__device__ __forceinline__ void unp8(bf16x8 v, float4& a, float4& b){
  const unsigned* u = (const unsigned*)&v;
  union{unsigned q; float f;} c;
  c.q = u[0]<<16;          a.x=c.f;
  c.q = u[0]&0xffff0000u;  a.y=c.f;
  c.q = u[1]<<16;          a.z=c.f;
  c.q = u[1]&0xffff0000u;  a.w=c.f;
  c.q = u[2]<<16;          b.x=c.f;
  c.q = u[2]&0xffff0000u;  b.y=c.f;
  c.q = u[3]<<16;          b.z=c.f;
  c.q = u[3]&0xffff0000u;  b.w=c.f;
}

#define MFMA32(A,B,C) __builtin_amdgcn_mfma_f32_32x32x16_bf16(A,B,C,0,0,0)
#define BC8(u) __builtin_bit_cast(bf16x8, u)

// ---------------------------------------------------------------------------
// LSTM weight pack: B[k][col] per step. k: 0..63 x, 64..191 hx, 192..193 ai,
// 194 bias, rest 0. frag (s,kstep,nt) = 64 lanes x 16B contiguous.
// ---------------------------------------------------------------------------
__global__ __launch_bounds__(256) void prep_pack(
    const float* __restrict__ wih, const float* __restrict__ whh,
    const float* __restrict__ bih, const float* __restrict__ bhh,
    ushort_t* __restrict__ bph, ushort_t* __restrict__ bpl)
{
  int id = blockIdx.x*256 + threadIdx.x;   // 25*13*16*64 = 332800
  int lane = id & 63;
  int r  = id >> 6;
  int nt = r & 15;
  int r2 = r >> 4;
  int kstep = r2 % 13;
  int s     = r2 / 13;
  int col = nt*32 + (lane&31);
  int k0  = kstep*16 + ((lane>>5)<<3);
  ushort_t hi[8], lo[8];
  #pragma unroll
  for (int j=0;j<8;j++){
    int k = k0+j;
    float w = 0.f;
    if (k < 64)       w = wih[((size_t)s*512+col)*66 + k];
    else if (k < 192) w = whh[((size_t)s*512+col)*128 + (k-64)];
    else if (k < 194) w = wih[((size_t)s*512+col)*66 + 64 + (k-192)];
    else if (k == 194) w = bih[(size_t)s*512+col] + bhh[(size_t)s*512+col];
    ushort_t h_ = f2b(w);
    hi[j] = h_;
    lo[j] = f2b(w - b2f(h_));
  }
  uint4 uh, ul;
  uh.x = hi[0] | ((unsigned)hi[1]<<16); uh.y = hi[2] | ((unsigned)hi[3]<<16);
  uh.z = hi[4] | ((unsigned)hi[5]<<16); uh.w = hi[6] | ((unsigned)hi[7]<<16);
  ul.x = lo[0] | ((unsigned)lo[1]<<16); ul.y = lo[2] | ((unsigned)lo[3]<<16);
  ul.z = lo[4] | ((unsigned)lo[5]<<16); ul.w = lo[6] | ((unsigned)lo[7]<<16);
  *(uint4*)&bph[(size_t)id*8] = uh;
  *(uint4*)&bpl[(size_t)id*8] = ul;
}

// ---------------------------------------------------------------------------
// Graphconv weight pack (unchanged, proven).
// ---------------------------------------------------------------------------
__global__ __launch_bounds__(256) void prep_gw(
    const float* __restrict__ wpb, const float* __restrict__ wnb,
    const float* __restrict__ wpd, const float* __restrict__ wnd,
    ushort_t* __restrict__ gw)
{
  int id = blockIdx.x*256 + threadIdx.x;   // 8192
  int lane = id & 63;
  int r = id >> 6;                          // 0..127
  int hl = r & 1, path = (r>>1)&1, slot = r>>2;
  int col = lane & 31;
  int kb = (lane>>5)*8;
  ushort_t outv[8];
  #pragma unroll
  for (int j=0;j<8;j++){
    float wv;
    if (slot < 4){
      int k = slot*16 + kb + j;
      wv = (path? wnb : wpb)[k*32 + col];
    } else {
      int sl = slot-4; int layer = sl/14, kstep = sl%14;
      int k = kstep*16 + kb + j;
      wv = (path? wnd : wpd)[((size_t)layer*224 + k)*32 + col];
    }
    ushort_t h = f2b(wv);
    outv[j] = hl ? f2b(wv - b2f(h)) : h;
  }
  uint4 u;
  u.x = outv[0]|((unsigned)outv[1]<<16); u.y = outv[2]|((unsigned)outv[3]<<16);
  u.z = outv[4]|((unsigned)outv[5]<<16); u.w = outv[6]|((unsigned)outv[7]<<16);
  *(uint4*)&gw[(size_t)id*8] = u;
}

// ---------------------------------------------------------------------------
// MFMA graphconv (unchanged from round 6, proven).
// ---------------------------------------------------------------------------
__global__ __launch_bounds__(384) void graphconv(
    const float* __restrict__ h0,
    const float* __restrict__ bpb, const float* __restrict__ bnb,
    const float* __restrict__ bpd, const float* __restrict__ bnd,
    const ushort_t* __restrict__ gw,
    const int* __restrict__ pos_adj, const int* __restrict__ neg_adj,
    ushort_t* __restrict__ xout)
{
  __shared__ __align__(16) ushort_t A [96*AST];
  __shared__ __align__(16) ushort_t A2[96*A2ST];
  __shared__ __align__(16) ushort_t A3[96*A2ST];
  __shared__ float Afp[GPB][10][10], Afn[GPB][10][10];
  __shared__ float dgrp[GPB][10], dgrn[GPB][10], dgcp[GPB][10], dgcn[GPB][10];

  const int t = threadIdx.x;
  const int lane = t & 63;
  const int wv = t >> 6;
  const int path = wv & 1;
  const int Mt = wv >> 1;
  const long g0 = (long)blockIdx.x * GPB;
  const int arow = Mt*32 + (lane&31);
  const int kof = (lane>>5)*8;
  const int col = lane & 31;
  const uint4* gw4 = (const uint4*)gw;

  for (int i=t; i<800; i+=384){
    int g_=i/100, e=i%100, rr=e/10, cc=e%10;
    float z = (rr==cc)?0.f:1.f;
    Afp[g_][rr][cc] = z*(float)pos_adj[(g0+g_)*100+e];
    Afn[g_][rr][cc] = z*(float)neg_adj[(g0+g_)*100+e];
  }
  if (t < 320){
    int row = t>>2, seg = t&3;
    const float* hr = h0 + (size_t)g0*320 + (size_t)row*32 + seg*8;
    float4 v0 = ((const float4*)hr)[0], v1 = ((const float4*)hr)[1];
    ushort_t h_[8], l_[8];
    float vv[8] = {v0.x,v0.y,v0.z,v0.w,v1.x,v1.y,v1.z,v1.w};
    #pragma unroll
    for (int j=0;j<8;j++){ h_[j]=f2b(vv[j]); l_[j]=f2b(vv[j]-b2f(h_[j])); }
    uint4 uh, ul;
    uh.x=h_[0]|((unsigned)h_[1]<<16); uh.y=h_[2]|((unsigned)h_[3]<<16);
    uh.z=h_[4]|((unsigned)h_[5]<<16); uh.w=h_[6]|((unsigned)h_[7]<<16);
    ul.x=l_[0]|((unsigned)l_[1]<<16); ul.y=l_[2]|((unsigned)l_[3]<<16);
    ul.z=l_[4]|((unsigned)l_[5]<<16); ul.w=l_[6]|((unsigned)l_[7]<<16);
    *(uint4*)&A [row*AST  + 32 + seg*8] = uh;
    *(uint4*)&A3[row*A2ST +      seg*8] = ul;
  }
  for (int i=t; i<16*116; i+=384) ((unsigned*)A)[(80+i/116)*116 + (i%116)] = 0u;
  for (int i=t; i<16*20; i+=384){
    ((unsigned*)A2)[(80+i/20)*20 + (i%20)] = 0u;
    ((unsigned*)A3)[(80+i/20)*20 + (i%20)] = 0u;
  }
  __syncthreads();
  if (t < 80){
    int g_=t/10, p_=t%10;
    float s0=0,s1=0,s2=0,s3=0;
    for (int q=0;q<10;q++){
      s0+=Afp[g_][p_][q]; s1+=Afn[g_][p_][q];
      s2+=Afp[g_][q][p_]; s3+=Afn[g_][q][p_];
    }
    dgrp[g_][p_]=1.f/fmaxf(s0,1.f); dgrn[g_][p_]=1.f/fmaxf(s1,1.f);
    dgcp[g_][p_]=1.f/fmaxf(s2,1.f); dgcn[g_][p_]=1.f/fmaxf(s3,1.f);
  }
  __syncthreads();

  if (t < 320){
    int gp=t>>2, cq=t&3, g_=gp/10, p_=gp%10;
    float4 aP0={0,0,0,0}, aP1=aP0, aN0=aP0, aN1=aP0;
    const float* hb = h0 + (size_t)(g0+g_)*320 + cq*8;
    #pragma unroll 1
    for (int q=0;q<10;q++){
      const float* hq = hb + q*32;
      float4 u0=((const float4*)hq)[0], u1=((const float4*)hq)[1];
      float ap=Afp[g_][p_][q], an=Afn[g_][p_][q];
      aP0=f4fma(ap,u0,aP0); aP1=f4fma(ap,u1,aP1);
      aN0=f4fma(an,u0,aN0); aN1=f4fma(an,u1,aN1);
    }
    float sp=dgrp[g_][p_], sn=dgrn[g_][p_];
    *(uint4*)&A [gp*AST  + cq*8] = packh(f4s(aP0,sp), f4s(aP1,sp));
    *(uint4*)&A2[gp*A2ST + cq*8] = packh(f4s(aN0,sn), f4s(aN1,sn));
  }
  __syncthreads();

  {
    f32x16 acc;
    #pragma unroll
    for (int i=0;i<16;i++) acc[i]=0.f;
    #pragma unroll
    for (int ks2=0; ks2<2; ++ks2){
      uint4 bh = gw4[((ks2*2+path)*2+0)*64 + lane];
      uint4 bl = gw4[((ks2*2+path)*2+1)*64 + lane];
      bf16x8 af = path ? *(const bf16x8*)&A2[arow*A2ST + ks2*16 + kof]
                       : *(const bf16x8*)&A [arow*AST  + ks2*16 + kof];
      acc = MFMA32(af, BC8(bh), acc);
      acc = MFMA32(af, BC8(bl), acc);
    }
    #pragma unroll
    for (int ks2=2; ks2<4; ++ks2){
      uint4 bh = gw4[((ks2*2+path)*2+0)*64 + lane];
      uint4 bl = gw4[((ks2*2+path)*2+1)*64 + lane];
      bf16x8 af = *(const bf16x8*)&A [arow*AST  + ks2*16 + kof];
      bf16x8 al = *(const bf16x8*)&A3[arow*A2ST + (ks2-2)*16 + kof];
      acc = MFMA32(af, BC8(bh), acc);
      acc = MFMA32(af, BC8(bl), acc);
      acc = MFMA32(al, BC8(bh), acc);
    }
    float bcol = path ? bnb[col] : bpb[col];
    ushort_t qv[16];
    #pragma unroll
    for (int i=0;i<16;i++){
      float v = acc[i] + bcol;
      float ss = v*v;
      ss += __shfl_xor(ss,1); ss += __shfl_xor(ss,2); ss += __shfl_xor(ss,4);
      ss += __shfl_xor(ss,8); ss += __shfl_xor(ss,16);
      float sc = 1.f/fmaxf(sqrtf(ss),1e-12f);
      qv[i] = f2b(v*sc);
    }
    __syncthreads();
    #pragma unroll
    for (int i=0;i<16;i++){
      int row = Mt*32 + (i&3) + 8*(i>>2) + 4*(lane>>5);
      if (path==0) A [row*AST  + 192 + col] = qv[i];
      else         A2[row*A2ST +       col] = qv[i];
    }
  }
  __syncthreads();

  #pragma unroll 1
  for (int layer=0; layer<2; ++layer){
    if (t < 320){
      int gp=t>>2, cq=t&3, g_=gp/10, p_=gp%10;
      float4 c0a={0,0,0,0},c0b=c0a,c1a=c0a,c1b=c0a,c2a=c0a,c2b=c0a;
      float4 c3a=c0a,c3b=c0a,c4a=c0a,c4b=c0a,c5a=c0a,c5b=c0a;
      #pragma unroll 1
      for (int q=0;q<10;q++){
        int rq = g_*10+q;
        bf16x8 hp8 = *(const bf16x8*)&A [rq*AST  + 192 + cq*8];
        bf16x8 hn8 = *(const bf16x8*)&A2[rq*A2ST +       cq*8];
        float4 hpa,hpb,hna,hnb;
        unp8(hp8,hpa,hpb); unp8(hn8,hna,hnb);
        float ap=Afp[g_][p_][q], an=Afn[g_][p_][q];
        float apT=Afp[g_][q][p_], anT=Afn[g_][q][p_];
        c0a=f4fma(ap ,hpa,c0a); c0b=f4fma(ap ,hpb,c0b);
        c1a=f4fma(an ,hna,c1a); c1b=f4fma(an ,hnb,c1b);
        c2a=f4fma(ap ,hna,c2a); c2b=f4fma(ap ,hnb,c2b);
        c3a=f4fma(an ,hpa,c3a); c3b=f4fma(an ,hpb,c3b);
        c4a=f4fma(apT,hpa,c4a); c4b=f4fma(apT,hpb,c4b);
        c5a=f4fma(anT,hna,c5a); c5b=f4fma(anT,hnb,c5b);
      }
      float srp=dgrp[g_][p_], srn=dgrn[g_][p_], scp=dgcp[g_][p_], scn=dgcn[g_][p_];
      *(uint4*)&A[gp*AST +   0 + cq*8] = packh(f4s(c0a,srp), f4s(c0b,srp));
      *(uint4*)&A[gp*AST +  32 + cq*8] = packh(f4s(c1a,srn), f4s(c1b,srn));
      *(uint4*)&A[gp*AST +  64 + cq*8] = packh(f4s(c2a,srp), f4s(c2b,srp));
      *(uint4*)&A[gp*AST +  96 + cq*8] = packh(f4s(c3a,srn), f4s(c3b,srn));
      *(uint4*)&A[gp*AST + 128 + cq*8] = packh(f4s(c4a,scp), f4s(c4b,scp));
      *(uint4*)&A[gp*AST + 160 + cq*8] = packh(f4s(c5a,scn), f4s(c5b,scn));
    }
    __syncthreads();

    f32x16 acc;
    #pragma unroll
    for (int i=0;i<16;i++) acc[i]=0.f;
    const int slot0 = 4 + layer*14;
    #pragma unroll
    for (int kstep=0; kstep<14; ++kstep){
      uint4 bh = gw4[(((slot0+kstep)*2+path)*2+0)*64 + lane];
      uint4 bl = gw4[(((slot0+kstep)*2+path)*2+1)*64 + lane];
      bf16x8 af;
      if (kstep<12 || path==0) af = *(const bf16x8*)&A [arow*AST  + kstep*16 + kof];
      else                     af = *(const bf16x8*)&A2[arow*A2ST + (kstep-12)*16 + kof];
      acc = MFMA32(af, BC8(bh), acc);
      acc = MFMA32(af, BC8(bl), acc);
    }
    float bcol = (path ? bnd : bpd)[layer*32 + col];
    ushort_t qv[16];
    #pragma unroll
    for (int i=0;i<16;i++){
      float v = acc[i] + bcol;
      float ss = v*v;
      ss += __shfl_xor(ss,1); ss += __shfl_xor(ss,2); ss += __shfl_xor(ss,4);
      ss += __shfl_xor(ss,8); ss += __shfl_xor(ss,16);
      float sc = 1.f/fmaxf(sqrtf(ss),1e-12f);
      qv[i] = f2b(v*sc);
    }
    if (layer==0){
      __syncthreads();
      #pragma unroll
      for (int i=0;i<16;i++){
        int row = Mt*32 + (i&3) + 8*(i>>2) + 4*(lane>>5);
        if (path==0) A [row*AST  + 192 + col] = qv[i];
        else         A2[row*A2ST +       col] = qv[i];
      }
      __syncthreads();
    } else {
      #pragma unroll
      for (int i=0;i<16;i++){
        int row = Mt*32 + (i&3) + 8*(i>>2) + 4*(lane>>5);
        if (row < 80){
          long gid = g0 + row/10;
          int p_ = row%10;
          size_t off = ((size_t)(gid%25)*NROW + (size_t)(gid/25)*10 + p_)*64
                     + path*32 + col;
          xout[off] = qv[i];
        }
      }
    }
  }
}

// ---------------------------------------------------------------------------
// Persistent MFMA LSTM v3: 256 blocks (1/CU) x 768 thr (12 waves), 80 rows
// padded to 96 (3 M-tiles), 25 steps. B staged through LDS double-buffered
// (reg-staged: issue loads for kstep+1 before kstep's MFMAs). Weight-lo pass
// kept only on the hx k-range (ksteps 4..11); hx itself hi/lo in LDS.
// ---------------------------------------------------------------------------
__global__ __launch_bounds__(LB,3) void lstm_persist(
    const ushort_t* __restrict__ xbuf, const ushort_t* __restrict__ bph,
    const ushort_t* __restrict__ bpl, const float* __restrict__ hx0,
    const float* __restrict__ cx0, const float* __restrict__ ai,
    float* __restrict__ outp)
{
  __shared__ __align__(16) ushort_t Ahi[96*ASTR];     // 41.5 KB
  __shared__ __align__(16) ushort_t Alo[96*LSTR];     // 26.1 KB
  __shared__ __align__(16) ushort_t Bh[2][8192];      // 32 KB
  __shared__ __align__(16) ushort_t Bl[2][8192];      // 32 KB

  const int t = threadIdx.x;
  const int lane = t & 63;
  const int w = t >> 6;            // 0..11
  const int mt = w >> 2;           // 0..2
  const int ng = w & 3;
  const long rbase = (long)blockIdx.x * LROWS;
  const int c = ng*32 + (lane&31);
  const int kof = (lane>>5)*8;
  const int arow = mt*32 + (lane&31);

  // ---- zero A planes, then fill ----
  for (int i=t; i<96*ASTR/2; i+=LB) ((unsigned*)Ahi)[i] = 0u;
  for (int i=t; i<96*LSTR/2; i+=LB) ((unsigned*)Alo)[i] = 0u;
  __syncthreads();
  if (t < LROWS){
    Ahi[t*ASTR+194] = 0x3F80;                // bias one (real rows only)
    long R = rbase + t; int g=(int)(R/10), p=(int)(R%10);
    const float* aip = ai + (((size_t)g*5+0)*10+p)*2;
    Ahi[t*ASTR+192]=f2b(aip[0]); Ahi[t*ASTR+193]=f2b(aip[1]);
  }
  if (t < 640){
    int row=t>>3, c0=(t&7)*8;
    *(uint4*)&Ahi[row*ASTR+c0] = *(const uint4*)&xbuf[((size_t)rbase+row)*64 + c0];
  }
  float cxr[16];
  #pragma unroll
  for (int i=0;i<16;i++){
    int rof=(i&3)+8*(i>>2)+4*(lane>>5);
    int lr2=mt*32+rof;
    if (lr2 < LROWS){
      long R=rbase+lr2;
      float h0v = hx0[(size_t)R*HHC+c];
      ushort_t hh=f2b(h0v);
      Ahi[lr2*ASTR+64+c]=hh;
      Alo[lr2*LSTR+c]=f2b(h0v-b2f(hh));
      cxr[i]=cx0[(size_t)R*HHC+c];
    } else cxr[i]=0.f;
  }
  // stage B(0,0) into buf 0 (k=0 is x-range: hi only)
  for (int idx=t; idx<1024; idx+=LB)
    *(uint4*)&Bh[0][idx*8] = *(const uint4*)&bph[(size_t)idx*8];
  __syncthreads();

  int buf = 0;
  #pragma unroll 1
  for (int s=0; s<NSTEP; ++s){
    f32x16 acc0, acc1, acc2, acc3;
    #pragma unroll
    for (int i=0;i<16;i++){ acc0[i]=0.f; acc1[i]=0.f; acc2[i]=0.f; acc3[i]=0.f; }

    #pragma unroll
    for (int kstep=0; kstep<13; ++kstep){
      // -- issue next-stage global loads (overlap with MFMAs below) --
      const int ns = (kstep==12)? s+1 : s;
      const int nk = (kstep==12)? 0 : kstep+1;
      const bool nlo = (nk>=4 && nk<12);
      uint4 sh0, sh1, sl0, sl1;
      if (ns < NSTEP){
        const ushort_t* srch = bph + ((size_t)ns*13+nk)*8192;
        sh0 = *(const uint4*)&srch[(size_t)t*8];
        if (t<256) sh1 = *(const uint4*)&srch[(size_t)(t+768)*8];
        if (nlo){
          const ushort_t* srcl = bpl + ((size_t)ns*13+nk)*8192;
          sl0 = *(const uint4*)&srcl[(size_t)t*8];
          if (t<256) sl1 = *(const uint4*)&srcl[(size_t)(t+768)*8];
        }
      }
      // -- compute current kstep --
      bf16x8 af = *(const bf16x8*)&Ahi[arow*ASTR + kstep*16 + kof];
      uint4 bh0 = *(const uint4*)&Bh[buf][(ng   )*512 + lane*8];
      uint4 bh1 = *(const uint4*)&Bh[buf][(ng+ 4)*512 + lane*8];
      uint4 bh2 = *(const uint4*)&Bh[buf][(ng+ 8)*512 + lane*8];
      uint4 bh3 = *(const uint4*)&Bh[buf][(ng+12)*512 + lane*8];
      acc0 = MFMA32(af, BC8(bh0), acc0);
      acc1 = MFMA32(af, BC8(bh1), acc1);
      acc2 = MFMA32(af, BC8(bh2), acc2);
      acc3 = MFMA32(af, BC8(bh3), acc3);
      if (kstep>=4 && kstep<12){
        bf16x8 al = *(const bf16x8*)&Alo[arow*LSTR + (kstep-4)*16 + kof];
        uint4 bl0 = *(const uint4*)&Bl[buf][(ng   )*512 + lane*8];
        uint4 bl1 = *(const uint4*)&Bl[buf][(ng+ 4)*512 + lane*8];
        uint4 bl2 = *(const uint4*)&Bl[buf][(ng+ 8)*512 + lane*8];
        uint4 bl3 = *(const uint4*)&Bl[buf][(ng+12)*512 + lane*8];
        acc0 = MFMA32(af, BC8(bl0), acc0);
        acc1 = MFMA32(af, BC8(bl1), acc1);
        acc2 = MFMA32(af, BC8(bl2), acc2);
        acc3 = MFMA32(af, BC8(bl3), acc3);
        acc0 = MFMA32(al, BC8(bh0), acc0);
        acc1 = MFMA32(al, BC8(bh1), acc1);
        acc2 = MFMA32(al, BC8(bh2), acc2);
        acc3 = MFMA32(al, BC8(bh3), acc3);
      }
      // -- write staged data into other buffer --
      if (ns < NSTEP){
        const int nb = buf^1;
        *(uint4*)&Bh[nb][(size_t)t*8] = sh0;
        if (t<256) *(uint4*)&Bh[nb][(size_t)(t+768)*8] = sh1;
        if (nlo){
          *(uint4*)&Bl[nb][(size_t)t*8] = sl0;
          if (t<256) *(uint4*)&Bl[nb][(size_t)(t+768)*8] = sl1;
        }
      }
      buf ^= 1;
      if (kstep<12) __syncthreads();
    }

    // -- cell update (writes hx/Alo: disjoint from kstep12's A reads) --
    #pragma unroll
    for (int i=0;i<16;i++){
      int rof=(i&3)+8*(i>>2)+4*(lane>>5);
      int lr2=mt*32+rof;
      float ig=sigf(acc0[i]), fg=sigf(acc1[i]);
      float gg=tanhf_(acc2[i]), og=sigf(acc3[i]);
      float cn = fg*cxr[i] + ig*gg;
      cxr[i]=cn;
      float h = og*tanhf_(cn);
      if (lr2 < LROWS){
        long R=rbase+lr2;
        if (s==NSTEP-1){
          outp[(size_t)R*HHC+c]=h;
        } else {
          ushort_t hh=f2b(h);
          Ahi[lr2*ASTR+64+c]=hh;
          Alo[lr2*LSTR+c]=f2b(h-b2f(hh));
        }
      }
    }
    if (s < NSTEP-1){
      __syncthreads();   // all kstep12 A reads done -> safe to touch x/ai cols
      if (t < 640){
        int row=t>>3, c0=(t&7)*8;
        *(uint4*)&Ahi[row*ASTR+c0] =
          *(const uint4*)&xbuf[((size_t)(s+1)*NROW + rbase + row)*64 + c0];
      }
      if (((s+1)%5)==0 && t<LROWS){
        long R=rbase+t; int g=(int)(R/10), p=(int)(R%10);
        const float* aip = ai + (((size_t)g*5+(s+1)/5)*10+p)*2;
        Ahi[t*ASTR+192]=f2b(aip[0]);
        Ahi[t*ASTR+193]=f2b(aip[1]);
      }
      __syncthreads();   // staged x/ai + hx visible for next step
    }
  }
}

// ---------------------------------------------------------------------------
extern "C" void kernel_launch(void* const* d_in, const int* in_sizes, int n_in,
                              void* d_out, int out_size, void* d_ws, size_t ws_size,
                              hipStream_t stream)
{
  const float* h0  = (const float*)d_in[0];
  const float* ai  = (const float*)d_in[1];
  const float* wpb = (const float*)d_in[2];
  const float* bpb = (const float*)d_in[3];
  const float* wnb = (const float*)d_in[4];
  const float* bnb = (const float*)d_in[5];
  const float* wpd = (const float*)d_in[6];
  const float* bpd = (const float*)d_in[7];
  const float* wnd = (const float*)d_in[8];
  const float* bnd = (const float*)d_in[9];
  const float* wih = (const float*)d_in[10];
  const float* whh = (const float*)d_in[11];
  const float* bih = (const float*)d_in[12];
  const float* bhh = (const float*)d_in[13];
  const float* hx0 = (const float*)d_in[14];
  const float* cx0 = (const float*)d_in[15];
  const int* padj  = (const int*)d_in[16];
  const int* nadj  = (const int*)d_in[17];
  float* out = (float*)d_out;

  ushort_t* xbuf16 = (ushort_t*)d_ws;                        // 25*20480*64 u16
  ushort_t* bph = xbuf16 + (size_t)NSTEP*NROW*64;            // 2,662,400 u16
  ushort_t* bpl = bph + (size_t)NSTEP*13*16*64*8;            // 2,662,400 u16
  ushort_t* gw  = bpl + (size_t)NSTEP*13*16*64*8;            // 65,536 u16

  prep_pack<<<1300,256,0,stream>>>(wih,whh,bih,bhh,bph,bpl);
  prep_gw<<<32,256,0,stream>>>(wpb,wnb,wpd,wnd,gw);
  graphconv<<<6400,384,0,stream>>>(h0,bpb,bnb,bpd,bnd,gw,padj,nadj,xbuf16);
  lstm_persist<<<256,LB,0,stream>>>(xbuf16,bph,bpl,hx0,cx0,ai,out);
}

// Round 8
// 971.164 us; speedup vs baseline: 5.9133x; 1.0936x over previous
//
#include <hip/hip_runtime.h>
#include <hip/hip_bf16.h>

#define GG 2048
#define PP 10
#define HHC 128
#define NSTEP 25
#define NROW (GG*PP)      // 20480
#define ASTR 216          // lstm Ahi stride (bf16)
#define LSTR 136          // lstm Alo stride
#define LROWS 80          // rows per lstm block
#define LB 768            // lstm threads per block
#define GPB 4             // graphs per graphconv block (2 pairs of 2)

typedef __attribute__((ext_vector_type(8))) short bf16x8;
typedef __attribute__((ext_vector_type(16))) float f32x16;
typedef unsigned short ushort_t;

__device__ __forceinline__ float sigf(float x){ return 1.f/(1.f+__expf(-x)); }
__device__ __forceinline__ float tanhf_(float x){ return 2.f/(1.f+__expf(-2.f*x)) - 1.f; }

__device__ __forceinline__ ushort_t f2b(float f){
  union{float f; unsigned u;} v; v.f=f;
  unsigned r = v.u + 0x7FFFu + ((v.u>>16)&1u);
  return (ushort_t)(r>>16);
}
__device__ __forceinline__ float b2f(ushort_t u){
  union{unsigned u; float f;} v; v.u = ((unsigned)u)<<16; return v.f;
}

#define MFMA32(A,B,C) __builtin_amdgcn_mfma_f32_32x32x16_bf16(A,B,C,0,0,0)
#define BC8(u) __builtin_bit_cast(bf16x8, u)

// ---------------------------------------------------------------------------
// LSTM weight pack (proven): B[k][col] per step. k: 0..63 x, 64..191 hx,
// 192..193 ai, 194 bias, rest 0.
// ---------------------------------------------------------------------------
__global__ __launch_bounds__(256) void prep_pack(
    const float* __restrict__ wih, const float* __restrict__ whh,
    const float* __restrict__ bih, const float* __restrict__ bhh,
    ushort_t* __restrict__ bph, ushort_t* __restrict__ bpl)
{
  int id = blockIdx.x*256 + threadIdx.x;   // 25*13*16*64 = 332800
  int lane = id & 63;
  int r  = id >> 6;
  int nt = r & 15;
  int r2 = r >> 4;
  int kstep = r2 % 13;
  int s     = r2 / 13;
  int col = nt*32 + (lane&31);
  int k0  = kstep*16 + ((lane>>5)<<3);
  ushort_t hi[8], lo[8];
  #pragma unroll
  for (int j=0;j<8;j++){
    int k = k0+j;
    float w = 0.f;
    if (k < 64)       w = wih[((size_t)s*512+col)*66 + k];
    else if (k < 192) w = whh[((size_t)s*512+col)*128 + (k-64)];
    else if (k < 194) w = wih[((size_t)s*512+col)*66 + 64 + (k-192)];
    else if (k == 194) w = bih[(size_t)s*512+col] + bhh[(size_t)s*512+col];
    ushort_t h_ = f2b(w);
    hi[j] = h_;
    lo[j] = f2b(w - b2f(h_));
  }
  uint4 uh, ul;
  uh.x = hi[0] | ((unsigned)hi[1]<<16); uh.y = hi[2] | ((unsigned)hi[3]<<16);
  uh.z = hi[4] | ((unsigned)hi[5]<<16); uh.w = hi[6] | ((unsigned)hi[7]<<16);
  ul.x = lo[0] | ((unsigned)lo[1]<<16); ul.y = lo[2] | ((unsigned)lo[3]<<16);
  ul.z = lo[4] | ((unsigned)lo[5]<<16); ul.w = lo[6] | ((unsigned)lo[7]<<16);
  *(uint4*)&bph[(size_t)id*8] = uh;
  *(uint4*)&bpl[(size_t)id*8] = ul;
}

// ---------------------------------------------------------------------------
// Graphconv weight pack (proven): slots 0..3 base, 4+layer*14+kstep deep.
// ---------------------------------------------------------------------------
__global__ __launch_bounds__(256) void prep_gw(
    const float* __restrict__ wpb, const float* __restrict__ wnb,
    const float* __restrict__ wpd, const float* __restrict__ wnd,
    ushort_t* __restrict__ gw)
{
  int id = blockIdx.x*256 + threadIdx.x;   // 8192
  int lane = id & 63;
  int r = id >> 6;                          // 0..127
  int hl = r & 1, path = (r>>1)&1, slot = r>>2;
  int col = lane & 31;
  int kb = (lane>>5)*8;
  ushort_t outv[8];
  #pragma unroll
  for (int j=0;j<8;j++){
    float wv;
    if (slot < 4){
      int k = slot*16 + kb + j;
      wv = (path? wnb : wpb)[k*32 + col];
    } else {
      int sl = slot-4; int layer = sl/14, kstep = sl%14;
      int k = kstep*16 + kb + j;
      wv = (path? wnd : wpd)[((size_t)layer*224 + k)*32 + col];
    }
    ushort_t h = f2b(wv);
    outv[j] = hl ? f2b(wv - b2f(h)) : h;
  }
  uint4 u;
  u.x = outv[0]|((unsigned)outv[1]<<16); u.y = outv[2]|((unsigned)outv[3]<<16);
  u.z = outv[4]|((unsigned)outv[5]<<16); u.w = outv[6]|((unsigned)outv[7]<<16);
  *(uint4*)&gw[(size_t)id*8] = u;
}

// ---------------------------------------------------------------------------
// Full-MFMA graphconv: 4 graphs/block (2 pairs x 16-pad rows = 64 rows),
// 256 thr = 4 waves = (pair, path). Aggregation is MFMA with block-diag
// bf16 adjacency (P,N,PT,NT); 1/deg folded fp32 at epilogue.
// LDS (64 KB): adjA[4][2][32*40], hrow[64*72], hT[64*72], Afeat[64*200],
// dinvA[4][64]. Base h0-lo plane lives in Afeat cols 64..95.
// ---------------------------------------------------------------------------
__global__ __launch_bounds__(256) void graphconv(
    const float* __restrict__ h0,
    const float* __restrict__ bpb, const float* __restrict__ bnb,
    const float* __restrict__ bpd, const float* __restrict__ bnd,
    const ushort_t* __restrict__ gw,
    const int* __restrict__ pos_adj, const int* __restrict__ neg_adj,
    ushort_t* __restrict__ xout)
{
  __shared__ __align__(16) ushort_t adjA[4][2][32*40];   // 20.5 KB
  __shared__ __align__(16) ushort_t hrow[64*72];         // 9.2 KB
  __shared__ __align__(16) ushort_t hT[64*72];           // 9.2 KB
  __shared__ __align__(16) ushort_t Afeat[64*200];       // 25.6 KB
  __shared__ float dinvA[4][64];                         // 1 KB

  const int t = threadIdx.x;
  const int lane = t & 63;
  const int w = t >> 6;            // 0..3
  const int pair = w >> 1;
  const int path = w & 1;
  const long g0 = (long)blockIdx.x * GPB;
  const int col = lane & 31;
  const int kof = (lane>>5)*8;
  const int arow = pair*32 + col;
  const uint4* gw4 = (const uint4*)gw;

  // ---- phase 0: zero LDS ----
  for (int i=t; i<10240; i+=256) ((unsigned*)adjA)[i] = 0u;   // adjA (5120d) + pad via next loops
  for (int i=t; i<2304; i+=256){ ((unsigned*)hrow)[i]=0u; ((unsigned*)hT)[i]=0u; }
  for (int i=t; i<6400; i+=256) ((unsigned*)Afeat)[i] = 0u;
  __syncthreads();

  // ---- phase 1: fill adjacency, h0, degrees ----
  for (int idx=t; idx<400; idx+=256){
    int g=idx/100, e=idx%100, r=e/10, c=e%10;
    if (r!=c){
      ushort_t pv = pos_adj[(g0+g)*100+e] ? (ushort_t)0x3F80 : (ushort_t)0;
      ushort_t nv = neg_adj[(g0+g)*100+e] ? (ushort_t)0x3F80 : (ushort_t)0;
      int pr=g>>1, gi=g&1;
      int rr=gi*16+r, cc=gi*16+c;
      adjA[0][pr][rr*40+cc]=pv;
      adjA[1][pr][rr*40+cc]=nv;
      adjA[2][pr][cc*40+rr]=pv;
      adjA[3][pr][cc*40+rr]=nv;
    }
  }
  if (t < 160){
    int r40=t>>2, seg=t&3;
    int g=r40/10, p=r40%10, prow=g*16+p;
    const float* hr = h0 + ((size_t)(g0+g)*10 + p)*32 + seg*8;
    float4 v0=((const float4*)hr)[0], v1=((const float4*)hr)[1];
    float vv[8]={v0.x,v0.y,v0.z,v0.w,v1.x,v1.y,v1.z,v1.w};
    #pragma unroll
    for (int j=0;j<8;j++){
      ushort_t hi_=f2b(vv[j]);
      hrow[prow*72 + seg*8+j] = hi_;
      hT[(seg*8+j)*72 + prow] = hi_;
      Afeat[prow*200 + 64 + seg*8+j] = f2b(vv[j]-b2f(hi_));
    }
  }
  if (t < 64){
    int g=t>>4, p=t&15;
    float rp=0,rn=0,cp=0,cn=0;
    if (p<10){
      const int* pb = pos_adj + (g0+g)*100;
      const int* nb = neg_adj + (g0+g)*100;
      for (int c=0;c<10;c++) if (c!=p){
        rp+=(float)pb[p*10+c]; rn+=(float)nb[p*10+c];
        cp+=(float)pb[c*10+p]; cn+=(float)nb[c*10+p];
      }
      rp=1.f/fmaxf(rp,1.f); rn=1.f/fmaxf(rn,1.f);
      cp=1.f/fmaxf(cp,1.f); cn=1.f/fmaxf(cn,1.f);
    }
    dinvA[0][t]=rp; dinvA[1][t]=rn; dinvA[2][t]=cp; dinvA[3][t]=cn;
  }
  __syncthreads();

  const int aoff = col*40 + kof;       // adjacency A-frag offset

  // ---- base aggregation (MFMA): path0 P*h0 -> Afeat 0..31, path1 N*h0 -> 32..63
  {
    f32x16 e;
    #pragma unroll
    for (int i=0;i<16;i++) e[i]=0.f;
    const ushort_t* aS = adjA[path][pair];
    #pragma unroll
    for (int ks=0;ks<2;++ks){
      bf16x8 av = *(const bf16x8*)&aS[aoff + ks*16];
      bf16x8 bv = *(const bf16x8*)&hT[col*72 + pair*32 + ks*16 + kof];
      e = MFMA32(av, bv, e);
    }
    #pragma unroll
    for (int i=0;i<16;i++){
      int row = pair*32 + (i&3) + 8*(i>>2) + 4*(lane>>5);
      Afeat[row*200 + path*32 + col] = f2b(e[i]*dinvA[path][row]);
    }
  }
  __syncthreads();

  // ---- base feature matmul: agg(2ks) + self h0(2ks) hi/lo + h0lo pass ----
  {
    f32x16 aa, ab;
    #pragma unroll
    for (int i=0;i<16;i++){ aa[i]=0.f; ab[i]=0.f; }
    #pragma unroll
    for (int ks=0;ks<2;++ks){
      uint4 bh = gw4[((ks*2+path)*2+0)*64 + lane];
      uint4 bl = gw4[((ks*2+path)*2+1)*64 + lane];
      bf16x8 af = *(const bf16x8*)&Afeat[arow*200 + path*32 + ks*16 + kof];
      aa = MFMA32(af, BC8(bh), aa);
      ab = MFMA32(af, BC8(bl), ab);
    }
    #pragma unroll
    for (int ks=0;ks<2;++ks){
      uint4 bh = gw4[(((ks+2)*2+path)*2+0)*64 + lane];
      uint4 bl = gw4[(((ks+2)*2+path)*2+1)*64 + lane];
      bf16x8 af  = *(const bf16x8*)&hrow[arow*72 + ks*16 + kof];
      bf16x8 alo = *(const bf16x8*)&Afeat[arow*200 + 64 + ks*16 + kof];
      aa = MFMA32(af,  BC8(bh), aa);
      ab = MFMA32(af,  BC8(bl), ab);
      aa = MFMA32(alo, BC8(bh), aa);
    }
    float bcol = path ? bnb[col] : bpb[col];
    ushort_t qv[16];
    #pragma unroll
    for (int i=0;i<16;i++){
      float v = aa[i] + ab[i] + bcol;
      float ss = v*v;
      ss += __shfl_xor(ss,1); ss += __shfl_xor(ss,2); ss += __shfl_xor(ss,4);
      ss += __shfl_xor(ss,8); ss += __shfl_xor(ss,16);
      float sc = 1.f/fmaxf(sqrtf(ss),1e-12f);
      qv[i] = f2b(v*sc);
    }
    __syncthreads();     // all reads of h0/Afeat done
    #pragma unroll
    for (int i=0;i<16;i++){
      int row = pair*32 + (i&3) + 8*(i>>2) + 4*(lane>>5);
      hrow[row*72 + path*32 + col] = qv[i];
      hT[(path*32+col)*72 + row]   = qv[i];
    }
  }
  __syncthreads();

  // ---- deep layers ----
  #pragma unroll 1
  for (int layer=0; layer<2; ++layer){
    // aggregation (MFMA): 3 output tiles per wave
    {
      f32x16 e0,e1,e2;
      #pragma unroll
      for (int i=0;i<16;i++){ e0[i]=0.f; e1[i]=0.f; e2[i]=0.f; }
      const ushort_t* aS = adjA[path][pair];
      const ushort_t* aT = adjA[2+path][pair];
      #pragma unroll
      for (int ks=0;ks<2;++ks){
        bf16x8 avS = *(const bf16x8*)&aS[aoff + ks*16];
        bf16x8 avT = *(const bf16x8*)&aT[aoff + ks*16];
        bf16x8 b0 = *(const bf16x8*)&hT[col*72      + pair*32 + ks*16 + kof];  // hp
        bf16x8 b1 = *(const bf16x8*)&hT[(32+col)*72 + pair*32 + ks*16 + kof];  // hn
        if (path==0){
          e0 = MFMA32(avS, b0, e0);   // P*hp  -> cols 0..31
          e1 = MFMA32(avS, b1, e1);   // P*hn  -> cols 64..95
          e2 = MFMA32(avT, b0, e2);   // PT*hp -> cols 128..159
        } else {
          e0 = MFMA32(avS, b1, e0);   // N*hn  -> cols 32..63
          e1 = MFMA32(avS, b0, e1);   // N*hp  -> cols 96..127
          e2 = MFMA32(avT, b1, e2);   // NT*hn -> cols 160..191
        }
      }
      const int c0 = path? 32 : 0;
      const int c1 = path? 96 : 64;
      const int c2 = path? 160 : 128;
      #pragma unroll
      for (int i=0;i<16;i++){
        int row = pair*32 + (i&3) + 8*(i>>2) + 4*(lane>>5);
        float sR = dinvA[path][row];
        float sC = dinvA[2+path][row];
        Afeat[row*200 + c0 + col] = f2b(e0[i]*sR);
        Afeat[row*200 + c1 + col] = f2b(e1[i]*sR);
        Afeat[row*200 + c2 + col] = f2b(e2[i]*sC);
      }
    }
    __syncthreads();

    // feature matmul: 12 agg ksteps + 2 self ksteps, hi+lo weights
    f32x16 aa, ab;
    #pragma unroll
    for (int i=0;i<16;i++){ aa[i]=0.f; ab[i]=0.f; }
    const int slot0 = 4 + layer*14;
    #pragma unroll
    for (int kstep=0; kstep<12; ++kstep){
      uint4 bh = gw4[(((slot0+kstep)*2+path)*2+0)*64 + lane];
      uint4 bl = gw4[(((slot0+kstep)*2+path)*2+1)*64 + lane];
      bf16x8 af = *(const bf16x8*)&Afeat[arow*200 + kstep*16 + kof];
      aa = MFMA32(af, BC8(bh), aa);
      ab = MFMA32(af, BC8(bl), ab);
    }
    #pragma unroll
    for (int ks=0;ks<2;++ks){
      uint4 bh = gw4[(((slot0+12+ks)*2+path)*2+0)*64 + lane];
      uint4 bl = gw4[(((slot0+12+ks)*2+path)*2+1)*64 + lane];
      bf16x8 af = *(const bf16x8*)&hrow[arow*72 + path*32 + ks*16 + kof];
      aa = MFMA32(af, BC8(bh), aa);
      ab = MFMA32(af, BC8(bl), ab);
    }
    float bcol = (path ? bnd : bpd)[layer*32 + col];
    ushort_t qv[16];
    #pragma unroll
    for (int i=0;i<16;i++){
      float v = aa[i] + ab[i] + bcol;
      float ss = v*v;
      ss += __shfl_xor(ss,1); ss += __shfl_xor(ss,2); ss += __shfl_xor(ss,4);
      ss += __shfl_xor(ss,8); ss += __shfl_xor(ss,16);
      float sc = 1.f/fmaxf(sqrtf(ss),1e-12f);
      qv[i] = f2b(v*sc);
    }
    if (layer==0){
      __syncthreads();   // all reads of hrow/hT/Afeat done
      #pragma unroll
      for (int i=0;i<16;i++){
        int row = pair*32 + (i&3) + 8*(i>>2) + 4*(lane>>5);
        hrow[row*72 + path*32 + col] = qv[i];
        hT[(path*32+col)*72 + row]   = qv[i];
      }
      __syncthreads();
    } else {
      #pragma unroll
      for (int i=0;i<16;i++){
        int row = pair*32 + (i&3) + 8*(i>>2) + 4*(lane>>5);
        int p_ = row & 15;
        if (p_ < 10){
          long gid = g0 + (row>>4);
          size_t off = ((size_t)(gid%25)*NROW + (size_t)(gid/25)*10 + p_)*64
                     + path*32 + col;
          xout[off] = qv[i];
        }
      }
    }
  }
}

// ---------------------------------------------------------------------------
// Persistent MFMA LSTM (unchanged from round 7, proven): 256 blocks x 768 thr,
// 80 rows padded 96, B double-buffered through LDS with reg-staging.
// ---------------------------------------------------------------------------
__global__ __launch_bounds__(LB,3) void lstm_persist(
    const ushort_t* __restrict__ xbuf, const ushort_t* __restrict__ bph,
    const ushort_t* __restrict__ bpl, const float* __restrict__ hx0,
    const float* __restrict__ cx0, const float* __restrict__ ai,
    float* __restrict__ outp)
{
  __shared__ __align__(16) ushort_t Ahi[96*ASTR];
  __shared__ __align__(16) ushort_t Alo[96*LSTR];
  __shared__ __align__(16) ushort_t Bh[2][8192];
  __shared__ __align__(16) ushort_t Bl[2][8192];

  const int t = threadIdx.x;
  const int lane = t & 63;
  const int w = t >> 6;
  const int mt = w >> 2;
  const int ng = w & 3;
  const long rbase = (long)blockIdx.x * LROWS;
  const int c = ng*32 + (lane&31);
  const int kof = (lane>>5)*8;
  const int arow = mt*32 + (lane&31);

  for (int i=t; i<96*ASTR/2; i+=LB) ((unsigned*)Ahi)[i] = 0u;
  for (int i=t; i<96*LSTR/2; i+=LB) ((unsigned*)Alo)[i] = 0u;
  __syncthreads();
  if (t < LROWS){
    Ahi[t*ASTR+194] = 0x3F80;
    long R = rbase + t; int g=(int)(R/10), p=(int)(R%10);
    const float* aip = ai + (((size_t)g*5+0)*10+p)*2;
    Ahi[t*ASTR+192]=f2b(aip[0]); Ahi[t*ASTR+193]=f2b(aip[1]);
  }
  if (t < 640){
    int row=t>>3, c0=(t&7)*8;
    *(uint4*)&Ahi[row*ASTR+c0] = *(const uint4*)&xbuf[((size_t)rbase+row)*64 + c0];
  }
  float cxr[16];
  #pragma unroll
  for (int i=0;i<16;i++){
    int rof=(i&3)+8*(i>>2)+4*(lane>>5);
    int lr2=mt*32+rof;
    if (lr2 < LROWS){
      long R=rbase+lr2;
      float h0v = hx0[(size_t)R*HHC+c];
      ushort_t hh=f2b(h0v);
      Ahi[lr2*ASTR+64+c]=hh;
      Alo[lr2*LSTR+c]=f2b(h0v-b2f(hh));
      cxr[i]=cx0[(size_t)R*HHC+c];
    } else cxr[i]=0.f;
  }
  for (int idx=t; idx<1024; idx+=LB)
    *(uint4*)&Bh[0][idx*8] = *(const uint4*)&bph[(size_t)idx*8];
  __syncthreads();

  int buf = 0;
  #pragma unroll 1
  for (int s=0; s<NSTEP; ++s){
    f32x16 acc0, acc1, acc2, acc3;
    #pragma unroll
    for (int i=0;i<16;i++){ acc0[i]=0.f; acc1[i]=0.f; acc2[i]=0.f; acc3[i]=0.f; }

    #pragma unroll
    for (int kstep=0; kstep<13; ++kstep){
      const int ns = (kstep==12)? s+1 : s;
      const int nk = (kstep==12)? 0 : kstep+1;
      const bool nlo = (nk>=4 && nk<12);
      uint4 sh0, sh1, sl0, sl1;
      if (ns < NSTEP){
        const ushort_t* srch = bph + ((size_t)ns*13+nk)*8192;
        sh0 = *(const uint4*)&srch[(size_t)t*8];
        if (t<256) sh1 = *(const uint4*)&srch[(size_t)(t+768)*8];
        if (nlo){
          const ushort_t* srcl = bpl + ((size_t)ns*13+nk)*8192;
          sl0 = *(const uint4*)&srcl[(size_t)t*8];
          if (t<256) sl1 = *(const uint4*)&srcl[(size_t)(t+768)*8];
        }
      }
      bf16x8 af = *(const bf16x8*)&Ahi[arow*ASTR + kstep*16 + kof];
      uint4 bh0 = *(const uint4*)&Bh[buf][(ng   )*512 + lane*8];
      uint4 bh1 = *(const uint4*)&Bh[buf][(ng+ 4)*512 + lane*8];
      uint4 bh2 = *(const uint4*)&Bh[buf][(ng+ 8)*512 + lane*8];
      uint4 bh3 = *(const uint4*)&Bh[buf][(ng+12)*512 + lane*8];
      acc0 = MFMA32(af, BC8(bh0), acc0);
      acc1 = MFMA32(af, BC8(bh1), acc1);
      acc2 = MFMA32(af, BC8(bh2), acc2);
      acc3 = MFMA32(af, BC8(bh3), acc3);
      if (kstep>=4 && kstep<12){
        bf16x8 al = *(const bf16x8*)&Alo[arow*LSTR + (kstep-4)*16 + kof];
        uint4 bl0 = *(const uint4*)&Bl[buf][(ng   )*512 + lane*8];
        uint4 bl1 = *(const uint4*)&Bl[buf][(ng+ 4)*512 + lane*8];
        uint4 bl2 = *(const uint4*)&Bl[buf][(ng+ 8)*512 + lane*8];
        uint4 bl3 = *(const uint4*)&Bl[buf][(ng+12)*512 + lane*8];
        acc0 = MFMA32(af, BC8(bl0), acc0);
        acc1 = MFMA32(af, BC8(bl1), acc1);
        acc2 = MFMA32(af, BC8(bl2), acc2);
        acc3 = MFMA32(af, BC8(bl3), acc3);
        acc0 = MFMA32(al, BC8(bh0), acc0);
        acc1 = MFMA32(al, BC8(bh1), acc1);
        acc2 = MFMA32(al, BC8(bh2), acc2);
        acc3 = MFMA32(al, BC8(bh3), acc3);
      }
      if (ns < NSTEP){
        const int nb = buf^1;
        *(uint4*)&Bh[nb][(size_t)t*8] = sh0;
        if (t<256) *(uint4*)&Bh[nb][(size_t)(t+768)*8] = sh1;
        if (nlo){
          *(uint4*)&Bl[nb][(size_t)t*8] = sl0;
          if (t<256) *(uint4*)&Bl[nb][(size_t)(t+768)*8] = sl1;
        }
      }
      buf ^= 1;
      if (kstep<12) __syncthreads();
    }

    #pragma unroll
    for (int i=0;i<16;i++){
      int rof=(i&3)+8*(i>>2)+4*(lane>>5);
      int lr2=mt*32+rof;
      float ig=sigf(acc0[i]), fg=sigf(acc1[i]);
      float gg=tanhf_(acc2[i]), og=sigf(acc3[i]);
      float cn = fg*cxr[i] + ig*gg;
      cxr[i]=cn;
      float h = og*tanhf_(cn);
      if (lr2 < LROWS){
        long R=rbase+lr2;
        if (s==NSTEP-1){
          outp[(size_t)R*HHC+c]=h;
        } else {
          ushort_t hh=f2b(h);
          Ahi[lr2*ASTR+64+c]=hh;
          Alo[lr2*LSTR+c]=f2b(h-b2f(hh));
        }
      }
    }
    if (s < NSTEP-1){
      __syncthreads();
      if (t < 640){
        int row=t>>3, c0=(t&7)*8;
        *(uint4*)&Ahi[row*ASTR+c0] =
          *(const uint4*)&xbuf[((size_t)(s+1)*NROW + rbase + row)*64 + c0];
      }
      if (((s+1)%5)==0 && t<LROWS){
        long R=rbase+t; int g=(int)(R/10), p=(int)(R%10);
        const float* aip = ai + (((size_t)g*5+(s+1)/5)*10+p)*2;
        Ahi[t*ASTR+192]=f2b(aip[0]);
        Ahi[t*ASTR+193]=f2b(aip[1]);
      }
      __syncthreads();
    }
  }
}

// ---------------------------------------------------------------------------
extern "C" void kernel_launch(void* const* d_in, const int* in_sizes, int n_in,
                              void* d_out, int out_size, void* d_ws, size_t ws_size,
                              hipStream_t stream)
{
  const float* h0  = (const float*)d_in[0];
  const float* ai  = (const float*)d_in[1];
  const float* wpb = (const float*)d_in[2];
  const float* bpb = (const float*)d_in[3];
  const float* wnb = (const float*)d_in[4];
  const float* bnb = (const float*)d_in[5];
  const float* wpd = (const float*)d_in[6];
  const float* bpd = (const float*)d_in[7];
  const float* wnd = (const float*)d_in[8];
  const float* bnd = (const float*)d_in[9];
  const float* wih = (const float*)d_in[10];
  const float* whh = (const float*)d_in[11];
  const float* bih = (const float*)d_in[12];
  const float* bhh = (const float*)d_in[13];
  const float* hx0 = (const float*)d_in[14];
  const float* cx0 = (const float*)d_in[15];
  const int* padj  = (const int*)d_in[16];
  const int* nadj  = (const int*)d_in[17];
  float* out = (float*)d_out;

  ushort_t* xbuf16 = (ushort_t*)d_ws;                        // 25*20480*64 u16
  ushort_t* bph = xbuf16 + (size_t)NSTEP*NROW*64;            // 2,662,400 u16
  ushort_t* bpl = bph + (size_t)NSTEP*13*16*64*8;            // 2,662,400 u16
  ushort_t* gw  = bpl + (size_t)NSTEP*13*16*64*8;            // 65,536 u16

  prep_pack<<<1300,256,0,stream>>>(wih,whh,bih,bhh,bph,bpl);
  prep_gw<<<32,256,0,stream>>>(wpb,wnb,wpd,wnd,gw);
  graphconv<<<12800,256,0,stream>>>(h0,bpb,bnb,bpd,bnd,gw,padj,nadj,xbuf16);
  lstm_persist<<<256,LB,0,stream>>>(xbuf16,bph,bpl,hx0,cx0,ai,out);
}

// Round 9
// 774.059 us; speedup vs baseline: 7.4190x; 1.2546x over previous
//
#include <hip/hip_runtime.h>
#include <hip/hip_bf16.h>

#define GG 2048
#define PP 10
#define HHC 128
#define NSTEP 25
#define NROW (GG*PP)      // 20480
#define ASTR 216          // lstm Ahi stride (bf16)
#define LSTR 136          // lstm Alo stride
#define LROWS 80          // rows per lstm block
#define LB 768            // lstm threads per block
#define GPB 4             // graphs per graphconv block
#define ADJS 40           // adjacency row stride (u16)
#define HS 72             // hrow/hT stride (u16)
#define AFS 200           // Afeat stride (u16)

typedef __attribute__((ext_vector_type(8))) short bf16x8;
typedef __attribute__((ext_vector_type(16))) float f32x16;
typedef unsigned short ushort_t;

__device__ __forceinline__ float sigf(float x){ return 1.f/(1.f+__expf(-x)); }
__device__ __forceinline__ float tanhf_(float x){ return 2.f/(1.f+__expf(-2.f*x)) - 1.f; }

__device__ __forceinline__ ushort_t f2b(float f){
  union{float f; unsigned u;} v; v.f=f;
  unsigned r = v.u + 0x7FFFu + ((v.u>>16)&1u);
  return (ushort_t)(r>>16);
}
__device__ __forceinline__ float b2f(ushort_t u){
  union{unsigned u; float f;} v; v.u = ((unsigned)u)<<16; return v.f;
}
__device__ __forceinline__ void st4(ushort_t* dst, float a, float b, float c, float d){
  ushort4 u; u.x=f2b(a); u.y=f2b(b); u.z=f2b(c); u.w=f2b(d);
  *(ushort4*)dst = u;
}

#define MFMA32(A,B,C) __builtin_amdgcn_mfma_f32_32x32x16_bf16(A,B,C,0,0,0)
#define BC8(u) __builtin_bit_cast(bf16x8, u)

// ---------------------------------------------------------------------------
// LSTM weight pack (proven, unchanged).
// ---------------------------------------------------------------------------
__global__ __launch_bounds__(256) void prep_pack(
    const float* __restrict__ wih, const float* __restrict__ whh,
    const float* __restrict__ bih, const float* __restrict__ bhh,
    ushort_t* __restrict__ bph, ushort_t* __restrict__ bpl)
{
  int id = blockIdx.x*256 + threadIdx.x;   // 25*13*16*64 = 332800
  int lane = id & 63;
  int r  = id >> 6;
  int nt = r & 15;
  int r2 = r >> 4;
  int kstep = r2 % 13;
  int s     = r2 / 13;
  int col = nt*32 + (lane&31);
  int k0  = kstep*16 + ((lane>>5)<<3);
  ushort_t hi[8], lo[8];
  #pragma unroll
  for (int j=0;j<8;j++){
    int k = k0+j;
    float w = 0.f;
    if (k < 64)       w = wih[((size_t)s*512+col)*66 + k];
    else if (k < 192) w = whh[((size_t)s*512+col)*128 + (k-64)];
    else if (k < 194) w = wih[((size_t)s*512+col)*66 + 64 + (k-192)];
    else if (k == 194) w = bih[(size_t)s*512+col] + bhh[(size_t)s*512+col];
    ushort_t h_ = f2b(w);
    hi[j] = h_;
    lo[j] = f2b(w - b2f(h_));
  }
  uint4 uh, ul;
  uh.x = hi[0] | ((unsigned)hi[1]<<16); uh.y = hi[2] | ((unsigned)hi[3]<<16);
  uh.z = hi[4] | ((unsigned)hi[5]<<16); uh.w = hi[6] | ((unsigned)hi[7]<<16);
  ul.x = lo[0] | ((unsigned)lo[1]<<16); ul.y = lo[2] | ((unsigned)lo[3]<<16);
  ul.z = lo[4] | ((unsigned)lo[5]<<16); ul.w = lo[6] | ((unsigned)lo[7]<<16);
  *(uint4*)&bph[(size_t)id*8] = uh;
  *(uint4*)&bpl[(size_t)id*8] = ul;
}

// ---------------------------------------------------------------------------
// Graphconv weight pack (unchanged — same frag doubles as A-operand).
// ---------------------------------------------------------------------------
__global__ __launch_bounds__(256) void prep_gw(
    const float* __restrict__ wpb, const float* __restrict__ wnb,
    const float* __restrict__ wpd, const float* __restrict__ wnd,
    ushort_t* __restrict__ gw)
{
  int id = blockIdx.x*256 + threadIdx.x;   // 8192
  int lane = id & 63;
  int r = id >> 6;                          // 0..127
  int hl = r & 1, path = (r>>1)&1, slot = r>>2;
  int col = lane & 31;
  int kb = (lane>>5)*8;
  ushort_t outv[8];
  #pragma unroll
  for (int j=0;j<8;j++){
    float wv;
    if (slot < 4){
      int k = slot*16 + kb + j;
      wv = (path? wnb : wpb)[k*32 + col];
    } else {
      int sl = slot-4; int layer = sl/14, kstep = sl%14;
      int k = kstep*16 + kb + j;
      wv = (path? wnd : wpd)[((size_t)layer*224 + k)*32 + col];
    }
    ushort_t h = f2b(wv);
    outv[j] = hl ? f2b(wv - b2f(h)) : h;
  }
  uint4 u;
  u.x = outv[0]|((unsigned)outv[1]<<16); u.y = outv[2]|((unsigned)outv[3]<<16);
  u.z = outv[4]|((unsigned)outv[5]<<16); u.w = outv[6]|((unsigned)outv[7]<<16);
  *(uint4*)&gw[(size_t)id*8] = u;
}

// ---------------------------------------------------------------------------
// Operand-swapped MFMA graphconv: D[out-feat][batch-row].
// A = weight frags (gw) or hT (agg); B = row-major activations / adjacency.
// Each lane owns ONE batch row -> in-register L2 norm (1 shfl).
// 4 graphs/block, 256 thr = 4 waves = (pair, path). LDS = 64 KB exactly.
// ---------------------------------------------------------------------------
__global__ __launch_bounds__(256) void graphconv(
    const float* __restrict__ h0,
    const float* __restrict__ bpb, const float* __restrict__ bnb,
    const float* __restrict__ bpd, const float* __restrict__ bnd,
    const ushort_t* __restrict__ gw,
    const int* __restrict__ pos_adj, const int* __restrict__ neg_adj,
    ushort_t* __restrict__ xout)
{
  __shared__ __align__(16) ushort_t adjA[4][2][32*ADJS]; // [P,N,PT,NT][pair][dst*40+src] 20.5K
  __shared__ __align__(16) ushort_t hT[64*HS];           // [feat][row64]             9.2K
  __shared__ __align__(16) ushort_t hrow[64*HS];         // [row64][feat]             9.2K
  __shared__ __align__(16) ushort_t Afeat[64*AFS];       // [row64][aggfeat 0..191]  25.6K
  __shared__ float dinv[4][64];                          //                           1K

  const int t = threadIdx.x;
  const int lane = t & 63;
  const int w = t >> 6;
  const int pair = w >> 1;
  const int path = w & 1;
  const long g0 = (long)blockIdx.x * GPB;
  const int nrow = lane & 31;
  const int row64 = pair*32 + nrow;
  const int kof = (lane>>5)*8;
  const int fbase = 4*(lane>>5);
  const uint4* gw4 = (const uint4*)gw;

  // ---- zero adjA + hT ----
  for (int i=t; i<10240; i+=256) ((unsigned*)adjA)[i] = 0u;
  for (int i=t; i<2304; i+=256)  ((unsigned*)hT)[i]   = 0u;
  __syncthreads();

  // ---- fills: adjacency (both layouts), h0 (hrow hi+lo, hT hi), degrees ----
  for (int idx=t; idx<400; idx+=256){
    int g=idx/100, e=idx%100, r=e/10, c=e%10;
    if (r!=c){
      ushort_t pv = pos_adj[(g0+g)*100+e] ? (ushort_t)0x3F80 : (ushort_t)0;
      ushort_t nv = neg_adj[(g0+g)*100+e] ? (ushort_t)0x3F80 : (ushort_t)0;
      int pr=g>>1, gi=g&1;
      int rr=gi*16+r, cc=gi*16+c;
      adjA[0][pr][rr*ADJS+cc]=pv;   // P  [dst][src]
      adjA[1][pr][rr*ADJS+cc]=nv;   // N
      adjA[2][pr][cc*ADJS+rr]=pv;   // PT [dst'][src']
      adjA[3][pr][cc*ADJS+rr]=nv;   // NT
    }
  }
  if (t < 160){
    int r40=t>>2, seg=t&3;
    int g=r40/10, p=r40%10;
    int r64 = g*16 + p;
    const float* hr = h0 + ((size_t)(g0+g)*10 + p)*32 + seg*8;
    float4 v0=((const float4*)hr)[0], v1=((const float4*)hr)[1];
    float vv[8]={v0.x,v0.y,v0.z,v0.w,v1.x,v1.y,v1.z,v1.w};
    #pragma unroll
    for (int j=0;j<8;j++){
      ushort_t hi_=f2b(vv[j]);
      hrow[r64*HS + seg*8+j]      = hi_;
      hrow[r64*HS + 32 + seg*8+j] = f2b(vv[j]-b2f(hi_));
      hT[(seg*8+j)*HS + r64]      = hi_;
    }
  }
  if (t < 64){
    int g=t>>4, p=t&15;
    float rp=0,rn=0,cp=0,cn=0;
    if (p<10){
      const int* pb = pos_adj + (g0+g)*100;
      const int* nb = neg_adj + (g0+g)*100;
      for (int c=0;c<10;c++) if (c!=p){
        rp+=(float)pb[p*10+c]; rn+=(float)nb[p*10+c];
        cp+=(float)pb[c*10+p]; cn+=(float)nb[c*10+p];
      }
      rp=1.f/fmaxf(rp,1.f); rn=1.f/fmaxf(rn,1.f);
      cp=1.f/fmaxf(cp,1.f); cn=1.f/fmaxf(cn,1.f);
    }
    dinv[0][t]=rp; dinv[1][t]=rn; dinv[2][t]=cp; dinv[3][t]=cn;
  }
  __syncthreads();

  // ---- base aggregation: D[feat][dst] = hT x adj ----
  {
    f32x16 e;
    #pragma unroll
    for (int i=0;i<16;i++) e[i]=0.f;
    #pragma unroll
    for (int ks=0;ks<2;++ks){
      bf16x8 a = *(const bf16x8*)&hT[nrow*HS + pair*32 + ks*16 + kof];         // feat=nrow
      bf16x8 b = *(const bf16x8*)&adjA[path][pair][nrow*ADJS + ks*16 + kof];   // dst=nrow
      e = MFMA32(a, b, e);
    }
    float s = dinv[path][row64];
    #pragma unroll
    for (int q=0;q<4;q++)
      st4(&Afeat[row64*AFS + path*32 + fbase + 8*q],
          e[4*q]*s, e[4*q+1]*s, e[4*q+2]*s, e[4*q+3]*s);
  }
  __syncthreads();

  // ---- base feature matmul: A=W^T frags, B=row-major activations ----
  {
    f32x16 acc;
    #pragma unroll
    for (int i=0;i<16;i++) acc[i]=0.f;
    #pragma unroll
    for (int ks=0;ks<2;++ks){
      uint4 wh = gw4[((ks*2+path)*2+0)*64 + lane];
      uint4 wl = gw4[((ks*2+path)*2+1)*64 + lane];
      bf16x8 b = *(const bf16x8*)&Afeat[row64*AFS + path*32 + ks*16 + kof];
      acc = MFMA32(BC8(wh), b, acc);
      acc = MFMA32(BC8(wl), b, acc);
    }
    #pragma unroll
    for (int ks=0;ks<2;++ks){
      uint4 wh = gw4[(((ks+2)*2+path)*2+0)*64 + lane];
      uint4 wl = gw4[(((ks+2)*2+path)*2+1)*64 + lane];
      bf16x8 b  = *(const bf16x8*)&hrow[row64*HS + ks*16 + kof];
      bf16x8 bl = *(const bf16x8*)&hrow[row64*HS + 32 + ks*16 + kof];
      acc = MFMA32(BC8(wh), b,  acc);
      acc = MFMA32(BC8(wl), b,  acc);
      acc = MFMA32(BC8(wh), bl, acc);
    }
    const float* bs = path ? bnb : bpb;
    float v[16]; float ss = 0.f;
    #pragma unroll
    for (int i=0;i<16;i++){
      int f = fbase + (i&3) + 8*(i>>2);
      v[i] = acc[i] + bs[f];
      ss += v[i]*v[i];
    }
    ss += __shfl_xor(ss,32);
    float sc = 1.f/fmaxf(sqrtf(ss),1e-12f);
    ushort_t qv[16];
    #pragma unroll
    for (int i=0;i<16;i++) qv[i] = f2b(v[i]*sc);
    __syncthreads();   // all reads of hrow/hT/Afeat done
    #pragma unroll
    for (int q=0;q<4;q++)
      *(ushort4*)&hrow[row64*HS + path*32 + fbase + 8*q] =
        make_ushort4(qv[4*q],qv[4*q+1],qv[4*q+2],qv[4*q+3]);
    #pragma unroll
    for (int i=0;i<16;i++){
      int f = fbase + (i&3) + 8*(i>>2);
      hT[(path*32+f)*HS + row64] = qv[i];
    }
  }
  __syncthreads();

  // ---- deep layers ----
  #pragma unroll 1
  for (int layer=0; layer<2; ++layer){
    // aggregation: 3 tiles per wave
    {
      f32x16 e0,e1,e2;
      #pragma unroll
      for (int i=0;i<16;i++){ e0[i]=0.f; e1[i]=0.f; e2[i]=0.f; }
      #pragma unroll
      for (int ks=0;ks<2;++ks){
        bf16x8 ahp = *(const bf16x8*)&hT[nrow*HS      + pair*32 + ks*16 + kof];
        bf16x8 ahn = *(const bf16x8*)&hT[(32+nrow)*HS + pair*32 + ks*16 + kof];
        bf16x8 bS  = *(const bf16x8*)&adjA[path][pair][nrow*ADJS + ks*16 + kof];
        bf16x8 bT  = *(const bf16x8*)&adjA[2+path][pair][nrow*ADJS + ks*16 + kof];
        if (path==0){
          e0 = MFMA32(ahp, bS, e0);   // P*hp  -> cols 0..31
          e1 = MFMA32(ahn, bS, e1);   // P*hn  -> cols 64..95
          e2 = MFMA32(ahp, bT, e2);   // PT*hp -> cols 128..159
        } else {
          e0 = MFMA32(ahn, bS, e0);   // N*hn  -> cols 32..63
          e1 = MFMA32(ahp, bS, e1);   // N*hp  -> cols 96..127
          e2 = MFMA32(ahn, bT, e2);   // NT*hn -> cols 160..191
        }
      }
      const int c0 = path? 32 : 0;
      const int c1 = path? 96 : 64;
      const int c2 = path? 160 : 128;
      float sR = dinv[path][row64];
      float sC = dinv[2+path][row64];
      #pragma unroll
      for (int q=0;q<4;q++){
        st4(&Afeat[row64*AFS + c0 + fbase + 8*q],
            e0[4*q]*sR, e0[4*q+1]*sR, e0[4*q+2]*sR, e0[4*q+3]*sR);
        st4(&Afeat[row64*AFS + c1 + fbase + 8*q],
            e1[4*q]*sR, e1[4*q+1]*sR, e1[4*q+2]*sR, e1[4*q+3]*sR);
        st4(&Afeat[row64*AFS + c2 + fbase + 8*q],
            e2[4*q]*sC, e2[4*q+1]*sC, e2[4*q+2]*sC, e2[4*q+3]*sC);
      }
    }
    __syncthreads();

    // feature matmul: K=224, hi+lo weight passes
    f32x16 acc;
    #pragma unroll
    for (int i=0;i<16;i++) acc[i]=0.f;
    const int slot0 = 4 + layer*14;
    #pragma unroll
    for (int kstep=0; kstep<12; ++kstep){
      uint4 wh = gw4[(((slot0+kstep)*2+path)*2+0)*64 + lane];
      uint4 wl = gw4[(((slot0+kstep)*2+path)*2+1)*64 + lane];
      bf16x8 b = *(const bf16x8*)&Afeat[row64*AFS + kstep*16 + kof];
      acc = MFMA32(BC8(wh), b, acc);
      acc = MFMA32(BC8(wl), b, acc);
    }
    #pragma unroll
    for (int ks=0;ks<2;++ks){
      uint4 wh = gw4[(((slot0+12+ks)*2+path)*2+0)*64 + lane];
      uint4 wl = gw4[(((slot0+12+ks)*2+path)*2+1)*64 + lane];
      bf16x8 b = *(const bf16x8*)&hrow[row64*HS + path*32 + ks*16 + kof];
      acc = MFMA32(BC8(wh), b, acc);
      acc = MFMA32(BC8(wl), b, acc);
    }
    const float* bs = (path ? bnd : bpd) + layer*32;
    float v[16]; float ss = 0.f;
    #pragma unroll
    for (int i=0;i<16;i++){
      int f = fbase + (i&3) + 8*(i>>2);
      v[i] = acc[i] + bs[f];
      ss += v[i]*v[i];
    }
    ss += __shfl_xor(ss,32);
    float sc = 1.f/fmaxf(sqrtf(ss),1e-12f);
    ushort_t qv[16];
    #pragma unroll
    for (int i=0;i<16;i++) qv[i] = f2b(v[i]*sc);

    if (layer==0){
      __syncthreads();   // all reads of hrow/hT/Afeat done
      #pragma unroll
      for (int q=0;q<4;q++)
        *(ushort4*)&hrow[row64*HS + path*32 + fbase + 8*q] =
          make_ushort4(qv[4*q],qv[4*q+1],qv[4*q+2],qv[4*q+3]);
      #pragma unroll
      for (int i=0;i<16;i++){
        int f = fbase + (i&3) + 8*(i>>2);
        hT[(path*32+f)*HS + row64] = qv[i];
      }
      __syncthreads();
    } else {
      int p_ = row64 & 15;
      if (p_ < 10){
        long gid = g0 + (row64>>4);
        size_t base = ((size_t)(gid%25)*NROW + (size_t)(gid/25)*10 + p_)*64 + path*32;
        #pragma unroll
        for (int q=0;q<4;q++)
          *(ushort4*)&xout[base + fbase + 8*q] =
            make_ushort4(qv[4*q],qv[4*q+1],qv[4*q+2],qv[4*q+3]);
      }
    }
  }
}

// ---------------------------------------------------------------------------
// Persistent MFMA LSTM (unchanged from round 7/8, proven).
// ---------------------------------------------------------------------------
__global__ __launch_bounds__(LB,3) void lstm_persist(
    const ushort_t* __restrict__ xbuf, const ushort_t* __restrict__ bph,
    const ushort_t* __restrict__ bpl, const float* __restrict__ hx0,
    const float* __restrict__ cx0, const float* __restrict__ ai,
    float* __restrict__ outp)
{
  __shared__ __align__(16) ushort_t Ahi[96*ASTR];
  __shared__ __align__(16) ushort_t Alo[96*LSTR];
  __shared__ __align__(16) ushort_t Bh[2][8192];
  __shared__ __align__(16) ushort_t Bl[2][8192];

  const int t = threadIdx.x;
  const int lane = t & 63;
  const int w = t >> 6;
  const int mt = w >> 2;
  const int ng = w & 3;
  const long rbase = (long)blockIdx.x * LROWS;
  const int c = ng*32 + (lane&31);
  const int kof = (lane>>5)*8;
  const int arow = mt*32 + (lane&31);

  for (int i=t; i<96*ASTR/2; i+=LB) ((unsigned*)Ahi)[i] = 0u;
  for (int i=t; i<96*LSTR/2; i+=LB) ((unsigned*)Alo)[i] = 0u;
  __syncthreads();
  if (t < LROWS){
    Ahi[t*ASTR+194] = 0x3F80;
    long R = rbase + t; int g=(int)(R/10), p=(int)(R%10);
    const float* aip = ai + (((size_t)g*5+0)*10+p)*2;
    Ahi[t*ASTR+192]=f2b(aip[0]); Ahi[t*ASTR+193]=f2b(aip[1]);
  }
  if (t < 640){
    int row=t>>3, c0=(t&7)*8;
    *(uint4*)&Ahi[row*ASTR+c0] = *(const uint4*)&xbuf[((size_t)rbase+row)*64 + c0];
  }
  float cxr[16];
  #pragma unroll
  for (int i=0;i<16;i++){
    int rof=(i&3)+8*(i>>2)+4*(lane>>5);
    int lr2=mt*32+rof;
    if (lr2 < LROWS){
      long R=rbase+lr2;
      float h0v = hx0[(size_t)R*HHC+c];
      ushort_t hh=f2b(h0v);
      Ahi[lr2*ASTR+64+c]=hh;
      Alo[lr2*LSTR+c]=f2b(h0v-b2f(hh));
      cxr[i]=cx0[(size_t)R*HHC+c];
    } else cxr[i]=0.f;
  }
  for (int idx=t; idx<1024; idx+=LB)
    *(uint4*)&Bh[0][idx*8] = *(const uint4*)&bph[(size_t)idx*8];
  __syncthreads();

  int buf = 0;
  #pragma unroll 1
  for (int s=0; s<NSTEP; ++s){
    f32x16 acc0, acc1, acc2, acc3;
    #pragma unroll
    for (int i=0;i<16;i++){ acc0[i]=0.f; acc1[i]=0.f; acc2[i]=0.f; acc3[i]=0.f; }

    #pragma unroll
    for (int kstep=0; kstep<13; ++kstep){
      const int ns = (kstep==12)? s+1 : s;
      const int nk = (kstep==12)? 0 : kstep+1;
      const bool nlo = (nk>=4 && nk<12);
      uint4 sh0, sh1, sl0, sl1;
      if (ns < NSTEP){
        const ushort_t* srch = bph + ((size_t)ns*13+nk)*8192;
        sh0 = *(const uint4*)&srch[(size_t)t*8];
        if (t<256) sh1 = *(const uint4*)&srch[(size_t)(t+768)*8];
        if (nlo){
          const ushort_t* srcl = bpl + ((size_t)ns*13+nk)*8192;
          sl0 = *(const uint4*)&srcl[(size_t)t*8];
          if (t<256) sl1 = *(const uint4*)&srcl[(size_t)(t+768)*8];
        }
      }
      bf16x8 af = *(const bf16x8*)&Ahi[arow*ASTR + kstep*16 + kof];
      uint4 bh0 = *(const uint4*)&Bh[buf][(ng   )*512 + lane*8];
      uint4 bh1 = *(const uint4*)&Bh[buf][(ng+ 4)*512 + lane*8];
      uint4 bh2 = *(const uint4*)&Bh[buf][(ng+ 8)*512 + lane*8];
      uint4 bh3 = *(const uint4*)&Bh[buf][(ng+12)*512 + lane*8];
      acc0 = MFMA32(af, BC8(bh0), acc0);
      acc1 = MFMA32(af, BC8(bh1), acc1);
      acc2 = MFMA32(af, BC8(bh2), acc2);
      acc3 = MFMA32(af, BC8(bh3), acc3);
      if (kstep>=4 && kstep<12){
        bf16x8 al = *(const bf16x8*)&Alo[arow*LSTR + (kstep-4)*16 + kof];
        uint4 bl0 = *(const uint4*)&Bl[buf][(ng   )*512 + lane*8];
        uint4 bl1 = *(const uint4*)&Bl[buf][(ng+ 4)*512 + lane*8];
        uint4 bl2 = *(const uint4*)&Bl[buf][(ng+ 8)*512 + lane*8];
        uint4 bl3 = *(const uint4*)&Bl[buf][(ng+12)*512 + lane*8];
        acc0 = MFMA32(af, BC8(bl0), acc0);
        acc1 = MFMA32(af, BC8(bl1), acc1);
        acc2 = MFMA32(af, BC8(bl2), acc2);
        acc3 = MFMA32(af, BC8(bl3), acc3);
        acc0 = MFMA32(al, BC8(bh0), acc0);
        acc1 = MFMA32(al, BC8(bh1), acc1);
        acc2 = MFMA32(al, BC8(bh2), acc2);
        acc3 = MFMA32(al, BC8(bh3), acc3);
      }
      if (ns < NSTEP){
        const int nb = buf^1;
        *(uint4*)&Bh[nb][(size_t)t*8] = sh0;
        if (t<256) *(uint4*)&Bh[nb][(size_t)(t+768)*8] = sh1;
        if (nlo){
          *(uint4*)&Bl[nb][(size_t)t*8] = sl0;
          if (t<256) *(uint4*)&Bl[nb][(size_t)(t+768)*8] = sl1;
        }
      }
      buf ^= 1;
      if (kstep<12) __syncthreads();
    }

    #pragma unroll
    for (int i=0;i<16;i++){
      int rof=(i&3)+8*(i>>2)+4*(lane>>5);
      int lr2=mt*32+rof;
      float ig=sigf(acc0[i]), fg=sigf(acc1[i]);
      float gg=tanhf_(acc2[i]), og=sigf(acc3[i]);
      float cn = fg*cxr[i] + ig*gg;
      cxr[i]=cn;
      float h = og*tanhf_(cn);
      if (lr2 < LROWS){
        long R=rbase+lr2;
        if (s==NSTEP-1){
          outp[(size_t)R*HHC+c]=h;
        } else {
          ushort_t hh=f2b(h);
          Ahi[lr2*ASTR+64+c]=hh;
          Alo[lr2*LSTR+c]=f2b(h-b2f(hh));
        }
      }
    }
    if (s < NSTEP-1){
      __syncthreads();
      if (t < 640){
        int row=t>>3, c0=(t&7)*8;
        *(uint4*)&Ahi[row*ASTR+c0] =
          *(const uint4*)&xbuf[((size_t)(s+1)*NROW + rbase + row)*64 + c0];
      }
      if (((s+1)%5)==0 && t<LROWS){
        long R=rbase+t; int g=(int)(R/10), p=(int)(R%10);
        const float* aip = ai + (((size_t)g*5+(s+1)/5)*10+p)*2;
        Ahi[t*ASTR+192]=f2b(aip[0]);
        Ahi[t*ASTR+193]=f2b(aip[1]);
      }
      __syncthreads();
    }
  }
}

// ---------------------------------------------------------------------------
extern "C" void kernel_launch(void* const* d_in, const int* in_sizes, int n_in,
                              void* d_out, int out_size, void* d_ws, size_t ws_size,
                              hipStream_t stream)
{
  const float* h0  = (const float*)d_in[0];
  const float* ai  = (const float*)d_in[1];
  const float* wpb = (const float*)d_in[2];
  const float* bpb = (const float*)d_in[3];
  const float* wnb = (const float*)d_in[4];
  const float* bnb = (const float*)d_in[5];
  const float* wpd = (const float*)d_in[6];
  const float* bpd = (const float*)d_in[7];
  const float* wnd = (const float*)d_in[8];
  const float* bnd = (const float*)d_in[9];
  const float* wih = (const float*)d_in[10];
  const float* whh = (const float*)d_in[11];
  const float* bih = (const float*)d_in[12];
  const float* bhh = (const float*)d_in[13];
  const float* hx0 = (const float*)d_in[14];
  const float* cx0 = (const float*)d_in[15];
  const int* padj  = (const int*)d_in[16];
  const int* nadj  = (const int*)d_in[17];
  float* out = (float*)d_out;

  ushort_t* xbuf16 = (ushort_t*)d_ws;                        // 25*20480*64 u16
  ushort_t* bph = xbuf16 + (size_t)NSTEP*NROW*64;            // 2,662,400 u16
  ushort_t* bpl = bph + (size_t)NSTEP*13*16*64*8;            // 2,662,400 u16
  ushort_t* gw  = bpl + (size_t)NSTEP*13*16*64*8;            // 65,536 u16

  prep_pack<<<1300,256,0,stream>>>(wih,whh,bih,bhh,bph,bpl);
  prep_gw<<<32,256,0,stream>>>(wpb,wnb,wpd,wnd,gw);
  graphconv<<<12800,256,0,stream>>>(h0,bpb,bnb,bpd,bnd,gw,padj,nadj,xbuf16);
  lstm_persist<<<256,LB,0,stream>>>(xbuf16,bph,bpl,hx0,cx0,ai,out);
}

// Round 10
// 685.428 us; speedup vs baseline: 8.3784x; 1.1293x over previous
//
#include <hip/hip_runtime.h>
#include <hip/hip_bf16.h>

#define GG 2048
#define PP 10
#define HHC 128
#define NSTEP 25
#define NROW (GG*PP)      // 20480
#define ASTR 216          // lstm Ahi stride (bf16)
#define LSTR 136          // lstm Alo stride
#define LROWS 80          // rows per lstm block
#define LB 768            // lstm threads per block
#define GPB 4             // graphs per graphconv block
#define ADJS 40           // adjacency row stride (u16)
#define HS 72             // hrow/hT stride (u16)
#define AFS 200           // Afeat stride (u16)

typedef __attribute__((ext_vector_type(8))) short bf16x8;
typedef __attribute__((ext_vector_type(16))) float f32x16;
typedef unsigned short ushort_t;

__device__ __forceinline__ float sigf(float x){ return 1.f/(1.f+__expf(-x)); }
__device__ __forceinline__ float tanhf_(float x){ return 2.f/(1.f+__expf(-2.f*x)) - 1.f; }

__device__ __forceinline__ ushort_t f2b(float f){
  union{float f; unsigned u;} v; v.f=f;
  unsigned r = v.u + 0x7FFFu + ((v.u>>16)&1u);
  return (ushort_t)(r>>16);
}
__device__ __forceinline__ float b2f(ushort_t u){
  union{unsigned u; float f;} v; v.u = ((unsigned)u)<<16; return v.f;
}
__device__ __forceinline__ void st4(ushort_t* dst, float a, float b, float c, float d){
  ushort4 u; u.x=f2b(a); u.y=f2b(b); u.z=f2b(c); u.w=f2b(d);
  *(ushort4*)dst = u;
}

#define MFMA32(A,B,C) __builtin_amdgcn_mfma_f32_32x32x16_bf16(A,B,C,0,0,0)
#define BC8(u) __builtin_bit_cast(bf16x8, u)

// ---------------------------------------------------------------------------
// LSTM weight pack (proven, unchanged): bpl kept for layout stability but the
// lstm no longer reads it (weight-lo pass dropped; al*bh pass retained).
// ---------------------------------------------------------------------------
__global__ __launch_bounds__(256) void prep_pack(
    const float* __restrict__ wih, const float* __restrict__ whh,
    const float* __restrict__ bih, const float* __restrict__ bhh,
    ushort_t* __restrict__ bph, ushort_t* __restrict__ bpl)
{
  int id = blockIdx.x*256 + threadIdx.x;   // 25*13*16*64 = 332800
  int lane = id & 63;
  int r  = id >> 6;
  int nt = r & 15;
  int r2 = r >> 4;
  int kstep = r2 % 13;
  int s     = r2 / 13;
  int col = nt*32 + (lane&31);
  int k0  = kstep*16 + ((lane>>5)<<3);
  ushort_t hi[8], lo[8];
  #pragma unroll
  for (int j=0;j<8;j++){
    int k = k0+j;
    float w = 0.f;
    if (k < 64)       w = wih[((size_t)s*512+col)*66 + k];
    else if (k < 192) w = whh[((size_t)s*512+col)*128 + (k-64)];
    else if (k < 194) w = wih[((size_t)s*512+col)*66 + 64 + (k-192)];
    else if (k == 194) w = bih[(size_t)s*512+col] + bhh[(size_t)s*512+col];
    ushort_t h_ = f2b(w);
    hi[j] = h_;
    lo[j] = f2b(w - b2f(h_));
  }
  uint4 uh, ul;
  uh.x = hi[0] | ((unsigned)hi[1]<<16); uh.y = hi[2] | ((unsigned)hi[3]<<16);
  uh.z = hi[4] | ((unsigned)hi[5]<<16); uh.w = hi[6] | ((unsigned)hi[7]<<16);
  ul.x = lo[0] | ((unsigned)lo[1]<<16); ul.y = lo[2] | ((unsigned)lo[3]<<16);
  ul.z = lo[4] | ((unsigned)lo[5]<<16); ul.w = lo[6] | ((unsigned)lo[7]<<16);
  *(uint4*)&bph[(size_t)id*8] = uh;
  *(uint4*)&bpl[(size_t)id*8] = ul;
}

// ---------------------------------------------------------------------------
// Graphconv weight pack (unchanged).
// ---------------------------------------------------------------------------
__global__ __launch_bounds__(256) void prep_gw(
    const float* __restrict__ wpb, const float* __restrict__ wnb,
    const float* __restrict__ wpd, const float* __restrict__ wnd,
    ushort_t* __restrict__ gw)
{
  int id = blockIdx.x*256 + threadIdx.x;   // 8192
  int lane = id & 63;
  int r = id >> 6;                          // 0..127
  int hl = r & 1, path = (r>>1)&1, slot = r>>2;
  int col = lane & 31;
  int kb = (lane>>5)*8;
  ushort_t outv[8];
  #pragma unroll
  for (int j=0;j<8;j++){
    float wv;
    if (slot < 4){
      int k = slot*16 + kb + j;
      wv = (path? wnb : wpb)[k*32 + col];
    } else {
      int sl = slot-4; int layer = sl/14, kstep = sl%14;
      int k = kstep*16 + kb + j;
      wv = (path? wnd : wpd)[((size_t)layer*224 + k)*32 + col];
    }
    ushort_t h = f2b(wv);
    outv[j] = hl ? f2b(wv - b2f(h)) : h;
  }
  uint4 u;
  u.x = outv[0]|((unsigned)outv[1]<<16); u.y = outv[2]|((unsigned)outv[3]<<16);
  u.z = outv[4]|((unsigned)outv[5]<<16); u.w = outv[6]|((unsigned)outv[7]<<16);
  *(uint4*)&gw[(size_t)id*8] = u;
}

// ---------------------------------------------------------------------------
// Operand-swapped MFMA graphconv (unchanged from round 9, proven ~250 us).
// ---------------------------------------------------------------------------
__global__ __launch_bounds__(256) void graphconv(
    const float* __restrict__ h0,
    const float* __restrict__ bpb, const float* __restrict__ bnb,
    const float* __restrict__ bpd, const float* __restrict__ bnd,
    const ushort_t* __restrict__ gw,
    const int* __restrict__ pos_adj, const int* __restrict__ neg_adj,
    ushort_t* __restrict__ xout)
{
  __shared__ __align__(16) ushort_t adjA[4][2][32*ADJS];
  __shared__ __align__(16) ushort_t hT[64*HS];
  __shared__ __align__(16) ushort_t hrow[64*HS];
  __shared__ __align__(16) ushort_t Afeat[64*AFS];
  __shared__ float dinv[4][64];

  const int t = threadIdx.x;
  const int lane = t & 63;
  const int w = t >> 6;
  const int pair = w >> 1;
  const int path = w & 1;
  const long g0 = (long)blockIdx.x * GPB;
  const int nrow = lane & 31;
  const int row64 = pair*32 + nrow;
  const int kof = (lane>>5)*8;
  const int fbase = 4*(lane>>5);
  const uint4* gw4 = (const uint4*)gw;

  for (int i=t; i<10240; i+=256) ((unsigned*)adjA)[i] = 0u;
  for (int i=t; i<2304; i+=256)  ((unsigned*)hT)[i]   = 0u;
  __syncthreads();

  for (int idx=t; idx<400; idx+=256){
    int g=idx/100, e=idx%100, r=e/10, c=e%10;
    if (r!=c){
      ushort_t pv = pos_adj[(g0+g)*100+e] ? (ushort_t)0x3F80 : (ushort_t)0;
      ushort_t nv = neg_adj[(g0+g)*100+e] ? (ushort_t)0x3F80 : (ushort_t)0;
      int pr=g>>1, gi=g&1;
      int rr=gi*16+r, cc=gi*16+c;
      adjA[0][pr][rr*ADJS+cc]=pv;
      adjA[1][pr][rr*ADJS+cc]=nv;
      adjA[2][pr][cc*ADJS+rr]=pv;
      adjA[3][pr][cc*ADJS+rr]=nv;
    }
  }
  if (t < 160){
    int r40=t>>2, seg=t&3;
    int g=r40/10, p=r40%10;
    int r64 = g*16 + p;
    const float* hr = h0 + ((size_t)(g0+g)*10 + p)*32 + seg*8;
    float4 v0=((const float4*)hr)[0], v1=((const float4*)hr)[1];
    float vv[8]={v0.x,v0.y,v0.z,v0.w,v1.x,v1.y,v1.z,v1.w};
    #pragma unroll
    for (int j=0;j<8;j++){
      ushort_t hi_=f2b(vv[j]);
      hrow[r64*HS + seg*8+j]      = hi_;
      hrow[r64*HS + 32 + seg*8+j] = f2b(vv[j]-b2f(hi_));
      hT[(seg*8+j)*HS + r64]      = hi_;
    }
  }
  if (t < 64){
    int g=t>>4, p=t&15;
    float rp=0,rn=0,cp=0,cn=0;
    if (p<10){
      const int* pb = pos_adj + (g0+g)*100;
      const int* nb = neg_adj + (g0+g)*100;
      for (int c=0;c<10;c++) if (c!=p){
        rp+=(float)pb[p*10+c]; rn+=(float)nb[p*10+c];
        cp+=(float)pb[c*10+p]; cn+=(float)nb[c*10+p];
      }
      rp=1.f/fmaxf(rp,1.f); rn=1.f/fmaxf(rn,1.f);
      cp=1.f/fmaxf(cp,1.f); cn=1.f/fmaxf(cn,1.f);
    }
    dinv[0][t]=rp; dinv[1][t]=rn; dinv[2][t]=cp; dinv[3][t]=cn;
  }
  __syncthreads();

  {
    f32x16 e;
    #pragma unroll
    for (int i=0;i<16;i++) e[i]=0.f;
    #pragma unroll
    for (int ks=0;ks<2;++ks){
      bf16x8 a = *(const bf16x8*)&hT[nrow*HS + pair*32 + ks*16 + kof];
      bf16x8 b = *(const bf16x8*)&adjA[path][pair][nrow*ADJS + ks*16 + kof];
      e = MFMA32(a, b, e);
    }
    float s = dinv[path][row64];
    #pragma unroll
    for (int q=0;q<4;q++)
      st4(&Afeat[row64*AFS + path*32 + fbase + 8*q],
          e[4*q]*s, e[4*q+1]*s, e[4*q+2]*s, e[4*q+3]*s);
  }
  __syncthreads();

  {
    f32x16 acc;
    #pragma unroll
    for (int i=0;i<16;i++) acc[i]=0.f;
    #pragma unroll
    for (int ks=0;ks<2;++ks){
      uint4 wh = gw4[((ks*2+path)*2+0)*64 + lane];
      uint4 wl = gw4[((ks*2+path)*2+1)*64 + lane];
      bf16x8 b = *(const bf16x8*)&Afeat[row64*AFS + path*32 + ks*16 + kof];
      acc = MFMA32(BC8(wh), b, acc);
      acc = MFMA32(BC8(wl), b, acc);
    }
    #pragma unroll
    for (int ks=0;ks<2;++ks){
      uint4 wh = gw4[(((ks+2)*2+path)*2+0)*64 + lane];
      uint4 wl = gw4[(((ks+2)*2+path)*2+1)*64 + lane];
      bf16x8 b  = *(const bf16x8*)&hrow[row64*HS + ks*16 + kof];
      bf16x8 bl = *(const bf16x8*)&hrow[row64*HS + 32 + ks*16 + kof];
      acc = MFMA32(BC8(wh), b,  acc);
      acc = MFMA32(BC8(wl), b,  acc);
      acc = MFMA32(BC8(wh), bl, acc);
    }
    const float* bs = path ? bnb : bpb;
    float v[16]; float ss = 0.f;
    #pragma unroll
    for (int i=0;i<16;i++){
      int f = fbase + (i&3) + 8*(i>>2);
      v[i] = acc[i] + bs[f];
      ss += v[i]*v[i];
    }
    ss += __shfl_xor(ss,32);
    float sc = 1.f/fmaxf(sqrtf(ss),1e-12f);
    ushort_t qv[16];
    #pragma unroll
    for (int i=0;i<16;i++) qv[i] = f2b(v[i]*sc);
    __syncthreads();
    #pragma unroll
    for (int q=0;q<4;q++)
      *(ushort4*)&hrow[row64*HS + path*32 + fbase + 8*q] =
        make_ushort4(qv[4*q],qv[4*q+1],qv[4*q+2],qv[4*q+3]);
    #pragma unroll
    for (int i=0;i<16;i++){
      int f = fbase + (i&3) + 8*(i>>2);
      hT[(path*32+f)*HS + row64] = qv[i];
    }
  }
  __syncthreads();

  #pragma unroll 1
  for (int layer=0; layer<2; ++layer){
    {
      f32x16 e0,e1,e2;
      #pragma unroll
      for (int i=0;i<16;i++){ e0[i]=0.f; e1[i]=0.f; e2[i]=0.f; }
      #pragma unroll
      for (int ks=0;ks<2;++ks){
        bf16x8 ahp = *(const bf16x8*)&hT[nrow*HS      + pair*32 + ks*16 + kof];
        bf16x8 ahn = *(const bf16x8*)&hT[(32+nrow)*HS + pair*32 + ks*16 + kof];
        bf16x8 bS  = *(const bf16x8*)&adjA[path][pair][nrow*ADJS + ks*16 + kof];
        bf16x8 bT  = *(const bf16x8*)&adjA[2+path][pair][nrow*ADJS + ks*16 + kof];
        if (path==0){
          e0 = MFMA32(ahp, bS, e0);
          e1 = MFMA32(ahn, bS, e1);
          e2 = MFMA32(ahp, bT, e2);
        } else {
          e0 = MFMA32(ahn, bS, e0);
          e1 = MFMA32(ahp, bS, e1);
          e2 = MFMA32(ahn, bT, e2);
        }
      }
      const int c0 = path? 32 : 0;
      const int c1 = path? 96 : 64;
      const int c2 = path? 160 : 128;
      float sR = dinv[path][row64];
      float sC = dinv[2+path][row64];
      #pragma unroll
      for (int q=0;q<4;q++){
        st4(&Afeat[row64*AFS + c0 + fbase + 8*q],
            e0[4*q]*sR, e0[4*q+1]*sR, e0[4*q+2]*sR, e0[4*q+3]*sR);
        st4(&Afeat[row64*AFS + c1 + fbase + 8*q],
            e1[4*q]*sR, e1[4*q+1]*sR, e1[4*q+2]*sR, e1[4*q+3]*sR);
        st4(&Afeat[row64*AFS + c2 + fbase + 8*q],
            e2[4*q]*sC, e2[4*q+1]*sC, e2[4*q+2]*sC, e2[4*q+3]*sC);
      }
    }
    __syncthreads();

    f32x16 acc;
    #pragma unroll
    for (int i=0;i<16;i++) acc[i]=0.f;
    const int slot0 = 4 + layer*14;
    #pragma unroll
    for (int kstep=0; kstep<12; ++kstep){
      uint4 wh = gw4[(((slot0+kstep)*2+path)*2+0)*64 + lane];
      uint4 wl = gw4[(((slot0+kstep)*2+path)*2+1)*64 + lane];
      bf16x8 b = *(const bf16x8*)&Afeat[row64*AFS + kstep*16 + kof];
      acc = MFMA32(BC8(wh), b, acc);
      acc = MFMA32(BC8(wl), b, acc);
    }
    #pragma unroll
    for (int ks=0;ks<2;++ks){
      uint4 wh = gw4[(((slot0+12+ks)*2+path)*2+0)*64 + lane];
      uint4 wl = gw4[(((slot0+12+ks)*2+path)*2+1)*64 + lane];
      bf16x8 b = *(const bf16x8*)&hrow[row64*HS + path*32 + ks*16 + kof];
      acc = MFMA32(BC8(wh), b, acc);
      acc = MFMA32(BC8(wl), b, acc);
    }
    const float* bs = (path ? bnd : bpd) + layer*32;
    float v[16]; float ss = 0.f;
    #pragma unroll
    for (int i=0;i<16;i++){
      int f = fbase + (i&3) + 8*(i>>2);
      v[i] = acc[i] + bs[f];
      ss += v[i]*v[i];
    }
    ss += __shfl_xor(ss,32);
    float sc = 1.f/fmaxf(sqrtf(ss),1e-12f);
    ushort_t qv[16];
    #pragma unroll
    for (int i=0;i<16;i++) qv[i] = f2b(v[i]*sc);

    if (layer==0){
      __syncthreads();
      #pragma unroll
      for (int q=0;q<4;q++)
        *(ushort4*)&hrow[row64*HS + path*32 + fbase + 8*q] =
          make_ushort4(qv[4*q],qv[4*q+1],qv[4*q+2],qv[4*q+3]);
      #pragma unroll
      for (int i=0;i<16;i++){
        int f = fbase + (i&3) + 8*(i>>2);
        hT[(path*32+f)*HS + row64] = qv[i];
      }
      __syncthreads();
    } else {
      int p_ = row64 & 15;
      if (p_ < 10){
        long gid = g0 + (row64>>4);
        size_t base = ((size_t)(gid%25)*NROW + (size_t)(gid/25)*10 + p_)*64 + path*32;
        #pragma unroll
        for (int q=0;q<4;q++)
          *(ushort4*)&xout[base + fbase + 8*q] =
            make_ushort4(qv[4*q],qv[4*q+1],qv[4*q+2],qv[4*q+3]);
      }
    }
  }
}

// ---------------------------------------------------------------------------
// Persistent MFMA LSTM v4: weight-lo (af*bl) pass DROPPED (x-range precedent
// from round 7 showed no absmax change); al*bh hx-residual pass kept.
// Bl buffer/staging removed (-32 KB LDS, -half staging traffic, -32 LDS
// reads/wave/step). setprio around MFMA cluster. First end-of-step barrier
// now conditional (only when ai cols are restaged; x cols are ordered by the
// kstep-3 barrier, hx cols by ksteps 0..3 barriers).
// ---------------------------------------------------------------------------
__global__ __launch_bounds__(LB,3) void lstm_persist(
    const ushort_t* __restrict__ xbuf, const ushort_t* __restrict__ bph,
    const float* __restrict__ hx0, const float* __restrict__ cx0,
    const float* __restrict__ ai, float* __restrict__ outp)
{
  __shared__ __align__(16) ushort_t Ahi[96*ASTR];
  __shared__ __align__(16) ushort_t Alo[96*LSTR];
  __shared__ __align__(16) ushort_t Bh[2][8192];

  const int t = threadIdx.x;
  const int lane = t & 63;
  const int w = t >> 6;
  const int mt = w >> 2;
  const int ng = w & 3;
  const long rbase = (long)blockIdx.x * LROWS;
  const int c = ng*32 + (lane&31);
  const int kof = (lane>>5)*8;
  const int arow = mt*32 + (lane&31);

  for (int i=t; i<96*ASTR/2; i+=LB) ((unsigned*)Ahi)[i] = 0u;
  for (int i=t; i<96*LSTR/2; i+=LB) ((unsigned*)Alo)[i] = 0u;
  __syncthreads();
  if (t < LROWS){
    Ahi[t*ASTR+194] = 0x3F80;
    long R = rbase + t; int g=(int)(R/10), p=(int)(R%10);
    const float* aip = ai + (((size_t)g*5+0)*10+p)*2;
    Ahi[t*ASTR+192]=f2b(aip[0]); Ahi[t*ASTR+193]=f2b(aip[1]);
  }
  if (t < 640){
    int row=t>>3, c0=(t&7)*8;
    *(uint4*)&Ahi[row*ASTR+c0] = *(const uint4*)&xbuf[((size_t)rbase+row)*64 + c0];
  }
  float cxr[16];
  #pragma unroll
  for (int i=0;i<16;i++){
    int rof=(i&3)+8*(i>>2)+4*(lane>>5);
    int lr2=mt*32+rof;
    if (lr2 < LROWS){
      long R=rbase+lr2;
      float h0v = hx0[(size_t)R*HHC+c];
      ushort_t hh=f2b(h0v);
      Ahi[lr2*ASTR+64+c]=hh;
      Alo[lr2*LSTR+c]=f2b(h0v-b2f(hh));
      cxr[i]=cx0[(size_t)R*HHC+c];
    } else cxr[i]=0.f;
  }
  for (int idx=t; idx<1024; idx+=LB)
    *(uint4*)&Bh[0][idx*8] = *(const uint4*)&bph[(size_t)idx*8];
  __syncthreads();

  int buf = 0;
  #pragma unroll 1
  for (int s=0; s<NSTEP; ++s){
    f32x16 acc0, acc1, acc2, acc3;
    #pragma unroll
    for (int i=0;i<16;i++){ acc0[i]=0.f; acc1[i]=0.f; acc2[i]=0.f; acc3[i]=0.f; }

    #pragma unroll
    for (int kstep=0; kstep<13; ++kstep){
      // issue next-stage loads (hi only) — hides under this kstep's MFMAs
      const int ns = (kstep==12)? s+1 : s;
      const int nk = (kstep==12)? 0 : kstep+1;
      uint4 sh0, sh1;
      if (ns < NSTEP){
        const ushort_t* srch = bph + ((size_t)ns*13+nk)*8192;
        sh0 = *(const uint4*)&srch[(size_t)t*8];
        if (t<256) sh1 = *(const uint4*)&srch[(size_t)(t+768)*8];
      }
      bf16x8 af = *(const bf16x8*)&Ahi[arow*ASTR + kstep*16 + kof];
      uint4 bh0 = *(const uint4*)&Bh[buf][(ng   )*512 + lane*8];
      uint4 bh1 = *(const uint4*)&Bh[buf][(ng+ 4)*512 + lane*8];
      uint4 bh2 = *(const uint4*)&Bh[buf][(ng+ 8)*512 + lane*8];
      uint4 bh3 = *(const uint4*)&Bh[buf][(ng+12)*512 + lane*8];
      __builtin_amdgcn_s_setprio(1);
      acc0 = MFMA32(af, BC8(bh0), acc0);
      acc1 = MFMA32(af, BC8(bh1), acc1);
      acc2 = MFMA32(af, BC8(bh2), acc2);
      acc3 = MFMA32(af, BC8(bh3), acc3);
      if (kstep>=4 && kstep<12){
        bf16x8 al = *(const bf16x8*)&Alo[arow*LSTR + (kstep-4)*16 + kof];
        acc0 = MFMA32(al, BC8(bh0), acc0);
        acc1 = MFMA32(al, BC8(bh1), acc1);
        acc2 = MFMA32(al, BC8(bh2), acc2);
        acc3 = MFMA32(al, BC8(bh3), acc3);
      }
      __builtin_amdgcn_s_setprio(0);
      if (ns < NSTEP){
        const int nb = buf^1;
        *(uint4*)&Bh[nb][(size_t)t*8] = sh0;
        if (t<256) *(uint4*)&Bh[nb][(size_t)(t+768)*8] = sh1;
      }
      buf ^= 1;
      if (kstep<12) __syncthreads();
    }

    // cell update (hx writes are ordered vs next step by ksteps 0..3 barriers)
    #pragma unroll
    for (int i=0;i<16;i++){
      int rof=(i&3)+8*(i>>2)+4*(lane>>5);
      int lr2=mt*32+rof;
      float ig=sigf(acc0[i]), fg=sigf(acc1[i]);
      float gg=tanhf_(acc2[i]), og=sigf(acc3[i]);
      float cn = fg*cxr[i] + ig*gg;
      cxr[i]=cn;
      float h = og*tanhf_(cn);
      if (lr2 < LROWS){
        long R=rbase+lr2;
        if (s==NSTEP-1){
          outp[(size_t)R*HHC+c]=h;
        } else {
          ushort_t hh=f2b(h);
          Ahi[lr2*ASTR+64+c]=hh;
          Alo[lr2*LSTR+c]=f2b(h-b2f(hh));
        }
      }
    }
    if (s < NSTEP-1){
      const bool newai = (((s+1)%5)==0);
      if (newai) __syncthreads();   // kstep12 reads ai cols — order only when restaged
      if (t < 640){
        int row=t>>3, c0=(t&7)*8;
        *(uint4*)&Ahi[row*ASTR+c0] =
          *(const uint4*)&xbuf[((size_t)(s+1)*NROW + rbase + row)*64 + c0];
      }
      if (newai && t<LROWS){
        long R=rbase+t; int g=(int)(R/10), p=(int)(R%10);
        const float* aip = ai + (((size_t)g*5+(s+1)/5)*10+p)*2;
        Ahi[t*ASTR+192]=f2b(aip[0]);
        Ahi[t*ASTR+193]=f2b(aip[1]);
      }
      __syncthreads();   // staged x/ai + hx visible before next step's kstep 0
    }
  }
}

// ---------------------------------------------------------------------------
extern "C" void kernel_launch(void* const* d_in, const int* in_sizes, int n_in,
                              void* d_out, int out_size, void* d_ws, size_t ws_size,
                              hipStream_t stream)
{
  const float* h0  = (const float*)d_in[0];
  const float* ai  = (const float*)d_in[1];
  const float* wpb = (const float*)d_in[2];
  const float* bpb = (const float*)d_in[3];
  const float* wnb = (const float*)d_in[4];
  const float* bnb = (const float*)d_in[5];
  const float* wpd = (const float*)d_in[6];
  const float* bpd = (const float*)d_in[7];
  const float* wnd = (const float*)d_in[8];
  const float* bnd = (const float*)d_in[9];
  const float* wih = (const float*)d_in[10];
  const float* whh = (const float*)d_in[11];
  const float* bih = (const float*)d_in[12];
  const float* bhh = (const float*)d_in[13];
  const float* hx0 = (const float*)d_in[14];
  const float* cx0 = (const float*)d_in[15];
  const int* padj  = (const int*)d_in[16];
  const int* nadj  = (const int*)d_in[17];
  float* out = (float*)d_out;

  ushort_t* xbuf16 = (ushort_t*)d_ws;                        // 25*20480*64 u16
  ushort_t* bph = xbuf16 + (size_t)NSTEP*NROW*64;            // 2,662,400 u16
  ushort_t* bpl = bph + (size_t)NSTEP*13*16*64*8;            // 2,662,400 u16 (unused by lstm now)
  ushort_t* gw  = bpl + (size_t)NSTEP*13*16*64*8;            // 65,536 u16

  prep_pack<<<1300,256,0,stream>>>(wih,whh,bih,bhh,bph,bpl);
  prep_gw<<<32,256,0,stream>>>(wpb,wnb,wpd,wnd,gw);
  graphconv<<<12800,256,0,stream>>>(h0,bpb,bnb,bpd,bnd,gw,padj,nadj,xbuf16);
  lstm_persist<<<256,LB,0,stream>>>(xbuf16,bph,hx0,cx0,ai,out);
}